// Round 13
// baseline (174.581 us; speedup 1.0000x reference)
//
#include <hip/hip_runtime.h>
#include <math.h>

// SS2D (VMamba v2) forward — MI355X gfx950.
// fp32 core; MFMA bf16-split in-proj; MFMA bf16 out-proj.
//
// Pipeline (8 dispatches):
//  k_castW   : W_in -> (hi,lo) bf16; W_out -> bf16
//  k_inproj3 : xz = x @ W_in^T via 3-term bf16 MFMA split
//  k_conv8   : depthwise 3x3 SAME + bias + silu -> xg (scan order)
//  k_xdbl    : x_dbl GEMM once -> dtr/Bm/Cm
//  k_scan1y  : local scan (h_in=0) -> writes y_local to yout, Q, S
//  k_scan2   : prefix over 64 chunks; P recomputed as exp(A*S)
//  k_scan3c  : chain-free correction: yout += C·(exp(A·S_l) ⊙ h0)
//  k_lnout   : merge + LayerNorm + gate -> bf16 LDS -> MFMA out GEMM

#define DINNER 192
#define NSTATE 16
#define KDIR 4
#define BATCH 4
#define NPIX (BATCH * 64 * 64)          // 16384
#define LP 1024
#define NCH 64                          // scan chunks
#define CHUNK 16                        // LP / NCH
#define NBK (BATCH * KDIR)              // 16
#define NSTATES (NBK * DINNER * NSTATE) // 49152
#define SSTRIDE (NBK * DINNER)          // 3072 floats of S per chunk
#define USTRIDE 196                     // sU row stride (floats)
#define GSTRIDE 200                     // lnout bf16 g LDS stride (shorts)

typedef __attribute__((ext_vector_type(8))) short short8;
typedef __attribute__((ext_vector_type(4))) short short4v;
typedef __attribute__((ext_vector_type(4))) float f32x4;

__device__ __forceinline__ float silu_f(float x) {
    return x / (1.0f + __expf(-x));
}
__device__ __forceinline__ float softplus_f(float a) {
    return (a > 20.0f) ? a : __logf(1.0f + __expf(a));
}
__device__ __forceinline__ unsigned short f2bf(float f) {
    unsigned u = __float_as_uint(f);
    unsigned r = (u + 0x7FFFu + ((u >> 16) & 1u)) >> 16;
    return (unsigned short)r;
}
__device__ __forceinline__ float bf2f(unsigned short h) {
    return __uint_as_float(((unsigned)h) << 16);
}

// Weights only: W_in hi/lo bf16 split (row-major), W_out bf16 cast.
__global__ __launch_bounds__(256) void k_castW(
        const float* __restrict__ W_in, const float* __restrict__ W_out,
        unsigned short* __restrict__ Wi_hi, unsigned short* __restrict__ Wi_lo,
        unsigned short* __restrict__ Wo_bf) {
    int i = blockIdx.x * 256 + threadIdx.x;
    if (i < 384 * 96) {
        float v = W_in[i];
        unsigned short h = f2bf(v);
        Wi_hi[i] = h;
        Wi_lo[i] = f2bf(v - bf2f(h));
    }
    if (i < 96 * DINNER) Wo_bf[i] = f2bf(W_out[i]);
}

// MFMA in-proj (bf16x3 split), x split inline from fp32.
__global__ __launch_bounds__(256) void k_inproj3(
        const float* __restrict__ x,
        const unsigned short* __restrict__ Wi_hi,
        const unsigned short* __restrict__ Wi_lo,
        float* __restrict__ xin, float* __restrict__ z) {
    int p0 = blockIdx.x * 16;
    int w = threadIdx.x >> 6;
    int lane = threadIdx.x & 63;
    int m = lane & 15, quad = lane >> 4;
    const short* wh = (const short*)Wi_hi;
    const short* wl = (const short*)Wi_lo;
    short8 ah[3], al[3];
    #pragma unroll
    for (int c = 0; c < 3; ++c) {
        const float* xr = x + (size_t)(p0 + m) * 96 + c * 32 + quad * 8;
        short8 hi, lo;
        #pragma unroll
        for (int j = 0; j < 8; ++j) {
            float v = xr[j];
            unsigned short hb = f2bf(v);
            hi[j] = (short)hb;
            lo[j] = (short)f2bf(v - bf2f(hb));
        }
        ah[c] = hi;
        al[c] = lo;
    }
    #pragma unroll
    for (int i = 0; i < 6; ++i) {
        int e0 = (w * 6 + i) * 16;
        f32x4 acc = {0.f, 0.f, 0.f, 0.f};
        #pragma unroll
        for (int c = 0; c < 3; ++c) {
            size_t o = (size_t)(e0 + m) * 96 + c * 32 + quad * 8;
            short8 bh = *(const short8*)(wh + o);
            short8 bl = *(const short8*)(wl + o);
            acc = __builtin_amdgcn_mfma_f32_16x16x32_bf16(ah[c], bl, acc, 0, 0, 0);
            acc = __builtin_amdgcn_mfma_f32_16x16x32_bf16(al[c], bh, acc, 0, 0, 0);
            acc = __builtin_amdgcn_mfma_f32_16x16x32_bf16(ah[c], bh, acc, 0, 0, 0);
        }
        int e = e0 + m;
        #pragma unroll
        for (int r = 0; r < 4; ++r) {
            int p = p0 + quad * 4 + r;
            if (e < 192) xin[(size_t)p * 192 + e] = acc[r];
            else         z[(size_t)p * 192 + (e - 192)] = silu_f(acc[r]);
        }
    }
}

// depthwise 3x3, 8 consecutive pixels of one row per block; sliding-window loads.
__global__ __launch_bounds__(192) void k_conv8(
        const float* __restrict__ xin, const float* __restrict__ cw,
        const float* __restrict__ cb, float* __restrict__ xg) {
    int blk = blockIdx.x;             // 2048 = 4 b * 64 h * 8 wchunks
    int b = blk >> 9;
    int rem = blk & 511;
    int h = rem >> 3;
    int w0 = (rem & 7) * 8;
    int d = threadIdx.x;
    float wr[3][3];
    #pragma unroll
    for (int i = 0; i < 3; ++i)
        #pragma unroll
        for (int j = 0; j < 3; ++j) wr[i][j] = cw[d * 9 + i * 3 + j];
    float bias = cb[d];
    float acc[8];
    #pragma unroll
    for (int o = 0; o < 8; ++o) acc[o] = bias;
    #pragma unroll
    for (int jj = 0; jj < 10; ++jj) {
        int ww = w0 + jj - 1;
        float r0 = 0.0f, r1 = 0.0f, r2 = 0.0f;
        if ((unsigned)ww < 64u) {
            const float* base = xin + ((size_t)b * 4096 + h * 64 + ww) * 192 + d;
            if (h > 0)  r0 = base[-64 * 192];
            r1 = base[0];
            if (h < 63) r2 = base[64 * 192];
        }
        #pragma unroll
        for (int dd2 = 0; dd2 < 3; ++dd2) {
            int o = jj - 2 + dd2;
            int cj = 2 - dd2;
            if (o >= 0 && o < 8) {
                acc[o] = fmaf(r0, wr[0][cj], acc[o]);
                acc[o] = fmaf(r1, wr[1][cj], acc[o]);
                acc[o] = fmaf(r2, wr[2][cj], acc[o]);
            }
        }
    }
    #pragma unroll
    for (int o = 0; o < 8; ++o) {
        int w = w0 + o;
        int kq = (h & 1) ? ((w & 1) ? 3 : 1) : ((w & 1) ? 2 : 0);
        int l = (kq & 1) ? ((w >> 1) * 32 + (h >> 1))
                         : ((h >> 1) * 32 + (w >> 1));
        xg[((size_t)(b * 4 + kq) * 1024 + l) * 192 + d] = silu_f(acc[o]);
    }
}

// x_dbl GEMM once: per (bk, 16-l tile), 38 rows -> dtr/Bm/Cm.
__global__ __launch_bounds__(192) void k_xdbl(
        const float* __restrict__ xg, const float* __restrict__ xpw,
        float* __restrict__ dtr, float* __restrict__ Bm, float* __restrict__ Cm) {
    __shared__ float sU[16 * USTRIDE];
    int bk = blockIdx.x >> 6;
    int tile = blockIdx.x & 63;
    int k = bk & 3;
    int t = threadIdx.x;
    int lbase = bk * 1024 + tile * 16;
    const float4* usrc = (const float4*)(xg + (size_t)lbase * 192);
    for (int i = t; i < 16 * 48; i += 192) {
        int l = i / 48, c4 = i - l * 48;
        *(float4*)&sU[l * USTRIDE + c4 * 4] = usrc[i];
    }
    __syncthreads();
    int l = t & 15, cgp = t >> 4;
    float acc[4] = {0.f, 0.f, 0.f, 0.f};
    int c3 = (cgp < 2) ? (cgp + 36) : cgp;
    const float* wb = xpw + (size_t)k * 38 * 192;
    for (int qv = 0; qv < 48; ++qv) {
        float4 xv = *(const float4*)&sU[l * USTRIDE + qv * 4];
        float4 w0 = *(const float4*)&wb[(cgp +  0) * 192 + qv * 4];
        float4 w1 = *(const float4*)&wb[(cgp + 12) * 192 + qv * 4];
        float4 w2 = *(const float4*)&wb[(cgp + 24) * 192 + qv * 4];
        float4 w3 = *(const float4*)&wb[(size_t)c3 * 192 + qv * 4];
        acc[0] = fmaf(xv.x, w0.x, fmaf(xv.y, w0.y, fmaf(xv.z, w0.z, fmaf(xv.w, w0.w, acc[0]))));
        acc[1] = fmaf(xv.x, w1.x, fmaf(xv.y, w1.y, fmaf(xv.z, w1.z, fmaf(xv.w, w1.w, acc[1]))));
        acc[2] = fmaf(xv.x, w2.x, fmaf(xv.y, w2.y, fmaf(xv.z, w2.z, fmaf(xv.w, w2.w, acc[2]))));
        acc[3] = fmaf(xv.x, w3.x, fmaf(xv.y, w3.y, fmaf(xv.z, w3.z, fmaf(xv.w, w3.w, acc[3]))));
    }
    int bkl = lbase + l;
    #pragma unroll
    for (int j = 0; j < 4; ++j) {
        int c = cgp + 12 * j;
        if (j == 3) { if (cgp >= 2) break; c = cgp + 36; }
        float v = acc[j];
        if (c < 6)       dtr[(size_t)bkl * 6 + c] = v;
        else if (c < 22) Bm[(size_t)bkl * 16 + (c - 6)] = v;
        else             Cm[(size_t)bkl * 16 + (c - 22)] = v;
    }
}

// Pass 1: local scan (h_in=0). Emits y_local (incl. u*D) to yout, Q, S.
__global__ __launch_bounds__(192) void k_scan1y(
        const float* __restrict__ xg, const float* __restrict__ dtr,
        const float* __restrict__ Bm, const float* __restrict__ Cm,
        const float* __restrict__ A_logs, const float* __restrict__ dtw,
        const float* __restrict__ dtb, const float* __restrict__ Ds,
        float* __restrict__ Sbuf, float* __restrict__ Qbuf,
        float* __restrict__ yout) {
    __shared__ float sU[CHUNK * USTRIDE];
    __shared__ float sB[CHUNK * 16];
    __shared__ float sC[CHUNK * 16];
    int bk = blockIdx.x >> 6;
    int ch = blockIdx.x & 63;
    int k = bk & 3;
    int d = threadIdx.x;
    int lbase = bk * 1024 + ch * CHUNK;
    const float4* usrc = (const float4*)(xg + (size_t)lbase * 192);
    for (int i = d; i < CHUNK * 48; i += 192) {
        int l = i / 48, c4 = i - l * 48;
        *(float4*)&sU[l * USTRIDE + c4 * 4] = usrc[i];
    }
    for (int i = d; i < CHUNK * 16; i += 192) {
        sB[i] = Bm[(size_t)lbase * 16 + i];
        sC[i] = Cm[(size_t)lbase * 16 + i];
    }
    float A[16];
    #pragma unroll
    for (int n = 0; n < 16; ++n) A[n] = -__expf(A_logs[(k * 192 + d) * 16 + n]);
    float A0 = A[0];
    bool geo = true;                 // A[n] == (n+1)*A[0] (geometric ladder)?
    #pragma unroll
    for (int n = 1; n < 16; ++n)
        geo = geo && (fabsf(A[n] - (float)(n + 1) * A0) <= 1e-4f * fabsf(A[n]));
    float wp[6];
    #pragma unroll
    for (int q = 0; q < 6; ++q) wp[q] = dtw[(k * 192 + d) * 6 + q];
    float bias = dtb[k * 192 + d];
    float Dp = Ds[k * 192 + d];
    __syncthreads();
    float h[16];
    #pragma unroll
    for (int n = 0; n < 16; ++n) h[n] = 0.0f;
    float S = 0.0f;
    for (int l = 0; l < CHUNK; ++l) {
        const float* r = dtr + (size_t)(lbase + l) * 6;   // wave-uniform
        float a = bias;
        #pragma unroll
        for (int q = 0; q < 6; ++q) a = fmaf(wp[q], r[q], a);
        float dlt = softplus_f(a);
        S += dlt;
        float u = sU[l * USTRIDE + d];
        float du = dlt * u;
        float y = 0.0f;
        if (geo) {
            float e1 = __expf(dlt * A0);
            float e = e1;
            #pragma unroll
            for (int n = 0; n < 16; ++n) {
                h[n] = fmaf(e, h[n], du * sB[l * 16 + n]);
                y = fmaf(h[n], sC[l * 16 + n], y);
                e *= e1;
            }
        } else {
            #pragma unroll
            for (int n = 0; n < 16; ++n) {
                float e = __expf(dlt * A[n]);
                h[n] = fmaf(e, h[n], du * sB[l * 16 + n]);
                y = fmaf(h[n], sC[l * 16 + n], y);
            }
        }
        yout[(size_t)(lbase + l) * 192 + d] = fmaf(u, Dp, y);
    }
    Sbuf[(size_t)ch * SSTRIDE + bk * 192 + d] = S;
    size_t base = (size_t)ch * NSTATES + bk * (192 * 16);
    #pragma unroll
    for (int n = 0; n < 16; ++n)
        Qbuf[base + n * 192 + d] = h[n];
}

// Pass 2: prefix over chunks; P recomputed as exp(A*S). In place (QH -> h_start).
__global__ __launch_bounds__(256) void k_scan2(
        const float* __restrict__ Sbuf, const float* __restrict__ A_logs,
        float* QH) {
    int s = blockIdx.x * 256 + threadIdx.x;   // 0..NSTATES-1
    int bk = s / 3072;                         // 3072 = 16*192
    int rem = s - bk * 3072;
    int n = rem / 192;
    int d = rem - n * 192;
    int k = bk & 3;
    float A = -__expf(A_logs[(k * 192 + d) * 16 + n]);
    float h = 0.0f;
    for (int c = 0; c < NCH; ++c) {
        float q = QH[(size_t)c * NSTATES + s];
        float S = Sbuf[(size_t)c * SSTRIDE + bk * 192 + d];
        float p = __expf(A * S);
        QH[(size_t)c * NSTATES + s] = h;
        h = fmaf(p, h, q);
    }
}

// Pass 3: chain-free correction. yout[l,d] += sum_n C[l,n]*exp(A[n]*S_l)*h0[n].
// Only serial dependency is S += dlt (one add). ch==0 blocks exit (h0=0).
__global__ __launch_bounds__(192) void k_scan3c(
        const float* __restrict__ dtr, const float* __restrict__ Cm,
        const float* __restrict__ A_logs, const float* __restrict__ dtw,
        const float* __restrict__ dtb, const float* __restrict__ QH,
        float* __restrict__ yout) {
    __shared__ float sC[CHUNK * 16];
    int bk = blockIdx.x >> 6;
    int ch = blockIdx.x & 63;
    if (ch == 0) return;              // h0 == 0, no correction
    int k = bk & 3;
    int d = threadIdx.x;
    int lbase = bk * 1024 + ch * CHUNK;
    for (int i = d; i < CHUNK * 16; i += 192)
        sC[i] = Cm[(size_t)lbase * 16 + i];
    float A[16];
    #pragma unroll
    for (int n = 0; n < 16; ++n) A[n] = -__expf(A_logs[(k * 192 + d) * 16 + n]);
    float A0 = A[0];
    bool geo = true;
    #pragma unroll
    for (int n = 1; n < 16; ++n)
        geo = geo && (fabsf(A[n] - (float)(n + 1) * A0) <= 1e-4f * fabsf(A[n]));
    float wp[6];
    #pragma unroll
    for (int q = 0; q < 6; ++q) wp[q] = dtw[(k * 192 + d) * 6 + q];
    float bias = dtb[k * 192 + d];
    float h0[16];
    size_t base = (size_t)ch * NSTATES + bk * (192 * 16);
    #pragma unroll
    for (int n = 0; n < 16; ++n) h0[n] = QH[base + n * 192 + d];
    __syncthreads();
    float S = 0.0f;
    for (int l = 0; l < CHUNK; ++l) {
        const float* r = dtr + (size_t)(lbase + l) * 6;   // wave-uniform
        float a = bias;
        #pragma unroll
        for (int q = 0; q < 6; ++q) a = fmaf(wp[q], r[q], a);
        S += softplus_f(a);
        float y = yout[(size_t)(lbase + l) * 192 + d];
        float corr = 0.0f;
        if (geo) {
            float e1 = __expf(A0 * S);
            float e = e1;
            #pragma unroll
            for (int n = 0; n < 16; ++n) {
                corr = fmaf(h0[n] * e, sC[l * 16 + n], corr);
                e *= e1;
            }
        } else {
            #pragma unroll
            for (int n = 0; n < 16; ++n) {
                float e = __expf(A[n] * S);
                corr = fmaf(h0[n] * e, sC[l * 16 + n], corr);
            }
        }
        yout[(size_t)(lbase + l) * 192 + d] = y + corr;
    }
}

// merge + LayerNorm + gate -> g (bf16, LDS) -> MFMA out GEMM. 32 pixels/block.
__global__ __launch_bounds__(256) void k_lnout(
        const float* __restrict__ yout, const float* __restrict__ z,
        const float* __restrict__ lng, const float* __restrict__ lnb,
        const unsigned short* __restrict__ Wo_bf, float* __restrict__ out) {
    __shared__ __align__(16) short sgb[32 * GSTRIDE];
    int p0 = blockIdx.x * 32;
    int t = threadIdx.x;
    int p = t >> 3;                    // pixel 0..31
    int sub = t & 7;                   // 8 threads per pixel, 24 channels each
    int gp = p0 + p;
    int b = gp >> 12;
    int hw = gp & 4095;
    int h = hw >> 6, w = hw & 63;
    int kq = (h & 1) ? ((w & 1) ? 3 : 1) : ((w & 1) ? 2 : 0);
    int l = (kq & 1) ? ((w >> 1) * 32 + (h >> 1))
                     : ((h >> 1) * 32 + (w >> 1));
    const float* yrow = yout + ((size_t)(b * 4 + kq) * 1024 + l) * 192 + sub * 24;
    float4 yv[6];
    float s = 0.0f, s2 = 0.0f;
    #pragma unroll
    for (int j = 0; j < 6; ++j) {
        float4 v = *(const float4*)(yrow + j * 4);
        yv[j] = v;
        s += v.x + v.y + v.z + v.w;
        s2 += v.x * v.x + v.y * v.y + v.z * v.z + v.w * v.w;
    }
    #pragma unroll
    for (int off = 1; off < 8; off <<= 1) {
        s  += __shfl_xor(s, off, 8);
        s2 += __shfl_xor(s2, off, 8);
    }
    float mu = s * (1.0f / 192.0f);
    float var = s2 * (1.0f / 192.0f) - mu * mu;
    float rstd = rsqrtf(var + 1e-5f);
    const float* zrow = z + (size_t)gp * 192 + sub * 24;
    short* grow = sgb + p * GSTRIDE + sub * 24;
    #pragma unroll
    for (int j = 0; j < 6; ++j) {
        float4 zv = *(const float4*)(zrow + j * 4);
        float4 gv = *(const float4*)(lng + sub * 24 + j * 4);
        float4 bv = *(const float4*)(lnb + sub * 24 + j * 4);
        short4v sv;
        sv.x = (short)f2bf(((yv[j].x - mu) * rstd * gv.x + bv.x) * zv.x);
        sv.y = (short)f2bf(((yv[j].y - mu) * rstd * gv.y + bv.y) * zv.y);
        sv.z = (short)f2bf(((yv[j].z - mu) * rstd * gv.z + bv.z) * zv.z);
        sv.w = (short)f2bf(((yv[j].w - mu) * rstd * gv.w + bv.w) * zv.w);
        *(short4v*)(grow + j * 4) = sv;
    }
    __syncthreads();
    int wv = t >> 6;
    int lane = t & 63;
    int m = lane & 15, quad = lane >> 4;
    int mt = wv >> 1;
    int nb = (wv & 1) * 3;
    const short* wob = (const short*)Wo_bf;
    short8 a[6];
    #pragma unroll
    for (int kk = 0; kk < 6; ++kk)
        a[kk] = *(const short8*)(sgb + (mt * 16 + m) * GSTRIDE + kk * 32 + quad * 8);
    #pragma unroll
    for (int i = 0; i < 3; ++i) {
        int n0 = (nb + i) * 16;
        f32x4 acc = {0.f, 0.f, 0.f, 0.f};
        #pragma unroll
        for (int kk = 0; kk < 6; ++kk) {
            short8 bfr = *(const short8*)(wob + (size_t)(n0 + m) * 192 + kk * 32 + quad * 8);
            acc = __builtin_amdgcn_mfma_f32_16x16x32_bf16(a[kk], bfr, acc, 0, 0, 0);
        }
        #pragma unroll
        for (int r = 0; r < 4; ++r) {
            int pp = p0 + mt * 16 + quad * 4 + r;
            out[(size_t)pp * 96 + n0 + m] = acc[r];
        }
    }
}

extern "C" void kernel_launch(void* const* d_in, const int* in_sizes, int n_in,
                              void* d_out, int out_size, void* d_ws, size_t ws_size,
                              hipStream_t stream) {
    const float* x    = (const float*)d_in[0];
    const float* W_in = (const float*)d_in[1];
    const float* cw   = (const float*)d_in[2];
    const float* cb   = (const float*)d_in[3];
    const float* xpw  = (const float*)d_in[4];
    const float* dtw  = (const float*)d_in[5];
    const float* dtb  = (const float*)d_in[6];
    const float* Alog = (const float*)d_in[7];
    const float* Ds   = (const float*)d_in[8];
    const float* lng  = (const float*)d_in[9];
    const float* lnb  = (const float*)d_in[10];
    const float* Wout = (const float*)d_in[11];
    float* out = (float*)d_out;

    float* ws = (float*)d_ws;
    size_t off = 0;
    unsigned short* Wi_hi = (unsigned short*)(ws + off); off += 384 * 96 / 2;
    unsigned short* Wi_lo = (unsigned short*)(ws + off); off += 384 * 96 / 2;
    unsigned short* Wo_bf = (unsigned short*)(ws + off); off += 96 * DINNER / 2;
    float* xin   = ws + off; off += (size_t)NPIX * 192;
    float* zbuf  = ws + off; off += (size_t)NPIX * 192;
    float* xg    = ws + off; off += (size_t)NPIX * 192;
    float* dtrb  = ws + off; off += (size_t)NBK * LP * 6;
    float* Bm    = ws + off; off += (size_t)NBK * LP * 16;
    float* Cm    = ws + off; off += (size_t)NBK * LP * 16;
    float* Sbuf  = ws + off; off += (size_t)NCH * SSTRIDE;
    float* QH    = ws + off; off += (size_t)NCH * NSTATES;
    float* yout  = ws + off; off += (size_t)NBK * LP * 192;

    hipLaunchKernelGGL(k_castW, dim3(144), dim3(256), 0, stream,
                       W_in, Wout, Wi_hi, Wi_lo, Wo_bf);
    hipLaunchKernelGGL(k_inproj3, dim3(NPIX / 16), dim3(256), 0, stream,
                       x, Wi_hi, Wi_lo, xin, zbuf);
    hipLaunchKernelGGL(k_conv8, dim3(NPIX / 8), dim3(192), 0, stream,
                       xin, cw, cb, xg);
    hipLaunchKernelGGL(k_xdbl, dim3(NBK * 64), dim3(192), 0, stream,
                       xg, xpw, dtrb, Bm, Cm);
    hipLaunchKernelGGL(k_scan1y, dim3(NBK * NCH), dim3(192), 0, stream,
                       xg, dtrb, Bm, Cm, Alog, dtw, dtb, Ds, Sbuf, QH, yout);
    hipLaunchKernelGGL(k_scan2, dim3(NSTATES / 256), dim3(256), 0, stream,
                       Sbuf, Alog, QH);
    hipLaunchKernelGGL(k_scan3c, dim3(NBK * NCH), dim3(192), 0, stream,
                       dtrb, Cm, Alog, dtw, dtb, QH, yout);
    hipLaunchKernelGGL(k_lnout, dim3(NPIX / 32), dim3(256), 0, stream,
                       yout, zbuf, lng, lnb, Wo_bf, out);
}

// Round 14
// 172.100 us; speedup vs baseline: 1.0144x; 1.0144x over previous
//
#include <hip/hip_runtime.h>
#include <math.h>

// SS2D (VMamba v2) forward — MI355X gfx950.
// fp32 scan core; MFMA bf16-split in-proj; MFMA bf16 out-proj.
// bf16 side-buffers (z gate, chunk-local Q) where error path to output is direct.
//
// Pipeline (8 dispatches):
//  k_castW   : W_in -> (hi,lo) bf16; W_out -> bf16
//  k_inproj3 : xz = x @ W_in^T via 3-term bf16 MFMA split; z stored bf16
//  k_conv8   : depthwise 3x3 SAME + bias + silu -> xg (scan order)
//  k_xdbl    : x_dbl GEMM once -> dtr/Bm/Cm
//  k_scan1y  : local scan (h_in=0) -> y_local to yout, Q (bf16), S
//  k_scan2   : prefix over 64 chunks (4x-batched loads); Hst = h at chunk start
//  k_scan3c  : chain-free correction: yout += C·(exp(A·S_l) ⊙ h0)
//  k_lnout   : merge + LayerNorm + gate(bf16 z) -> bf16 LDS -> MFMA out GEMM

#define DINNER 192
#define NSTATE 16
#define KDIR 4
#define BATCH 4
#define NPIX (BATCH * 64 * 64)          // 16384
#define LP 1024
#define NCH 64                          // scan chunks
#define CHUNK 16                        // LP / NCH
#define NBK (BATCH * KDIR)              // 16
#define NSTATES (NBK * DINNER * NSTATE) // 49152
#define SSTRIDE (NBK * DINNER)          // 3072 floats of S per chunk
#define USTRIDE 196                     // sU row stride (floats)
#define GSTRIDE 200                     // lnout bf16 g LDS stride (shorts)

typedef __attribute__((ext_vector_type(8))) short short8;
typedef __attribute__((ext_vector_type(4))) short short4v;
typedef __attribute__((ext_vector_type(4))) unsigned short ushort4v;
typedef __attribute__((ext_vector_type(4))) float f32x4;

__device__ __forceinline__ float silu_f(float x) {
    return x / (1.0f + __expf(-x));
}
__device__ __forceinline__ float softplus_f(float a) {
    return (a > 20.0f) ? a : __logf(1.0f + __expf(a));
}
__device__ __forceinline__ unsigned short f2bf(float f) {
    unsigned u = __float_as_uint(f);
    unsigned r = (u + 0x7FFFu + ((u >> 16) & 1u)) >> 16;
    return (unsigned short)r;
}
__device__ __forceinline__ float bf2f(unsigned short h) {
    return __uint_as_float(((unsigned)h) << 16);
}

// Weights only: W_in hi/lo bf16 split (row-major), W_out bf16 cast.
__global__ __launch_bounds__(256) void k_castW(
        const float* __restrict__ W_in, const float* __restrict__ W_out,
        unsigned short* __restrict__ Wi_hi, unsigned short* __restrict__ Wi_lo,
        unsigned short* __restrict__ Wo_bf) {
    int i = blockIdx.x * 256 + threadIdx.x;
    if (i < 384 * 96) {
        float v = W_in[i];
        unsigned short h = f2bf(v);
        Wi_hi[i] = h;
        Wi_lo[i] = f2bf(v - bf2f(h));
    }
    if (i < 96 * DINNER) Wo_bf[i] = f2bf(W_out[i]);
}

// MFMA in-proj (bf16x3 split), x split inline from fp32; z written bf16.
__global__ __launch_bounds__(256) void k_inproj3(
        const float* __restrict__ x,
        const unsigned short* __restrict__ Wi_hi,
        const unsigned short* __restrict__ Wi_lo,
        float* __restrict__ xin, unsigned short* __restrict__ zb) {
    int p0 = blockIdx.x * 16;
    int w = threadIdx.x >> 6;
    int lane = threadIdx.x & 63;
    int m = lane & 15, quad = lane >> 4;
    const short* wh = (const short*)Wi_hi;
    const short* wl = (const short*)Wi_lo;
    short8 ah[3], al[3];
    #pragma unroll
    for (int c = 0; c < 3; ++c) {
        const float* xr = x + (size_t)(p0 + m) * 96 + c * 32 + quad * 8;
        short8 hi, lo;
        #pragma unroll
        for (int j = 0; j < 8; ++j) {
            float v = xr[j];
            unsigned short hb = f2bf(v);
            hi[j] = (short)hb;
            lo[j] = (short)f2bf(v - bf2f(hb));
        }
        ah[c] = hi;
        al[c] = lo;
    }
    #pragma unroll
    for (int i = 0; i < 6; ++i) {
        int e0 = (w * 6 + i) * 16;
        f32x4 acc = {0.f, 0.f, 0.f, 0.f};
        #pragma unroll
        for (int c = 0; c < 3; ++c) {
            size_t o = (size_t)(e0 + m) * 96 + c * 32 + quad * 8;
            short8 bh = *(const short8*)(wh + o);
            short8 bl = *(const short8*)(wl + o);
            acc = __builtin_amdgcn_mfma_f32_16x16x32_bf16(ah[c], bl, acc, 0, 0, 0);
            acc = __builtin_amdgcn_mfma_f32_16x16x32_bf16(al[c], bh, acc, 0, 0, 0);
            acc = __builtin_amdgcn_mfma_f32_16x16x32_bf16(ah[c], bh, acc, 0, 0, 0);
        }
        int e = e0 + m;
        #pragma unroll
        for (int r = 0; r < 4; ++r) {
            int p = p0 + quad * 4 + r;
            if (e < 192) xin[(size_t)p * 192 + e] = acc[r];
            else         zb[(size_t)p * 192 + (e - 192)] = f2bf(silu_f(acc[r]));
        }
    }
}

// depthwise 3x3, 8 consecutive pixels of one row per block; sliding-window loads.
__global__ __launch_bounds__(192) void k_conv8(
        const float* __restrict__ xin, const float* __restrict__ cw,
        const float* __restrict__ cb, float* __restrict__ xg) {
    int blk = blockIdx.x;             // 2048 = 4 b * 64 h * 8 wchunks
    int b = blk >> 9;
    int rem = blk & 511;
    int h = rem >> 3;
    int w0 = (rem & 7) * 8;
    int d = threadIdx.x;
    float wr[3][3];
    #pragma unroll
    for (int i = 0; i < 3; ++i)
        #pragma unroll
        for (int j = 0; j < 3; ++j) wr[i][j] = cw[d * 9 + i * 3 + j];
    float bias = cb[d];
    float acc[8];
    #pragma unroll
    for (int o = 0; o < 8; ++o) acc[o] = bias;
    #pragma unroll
    for (int jj = 0; jj < 10; ++jj) {
        int ww = w0 + jj - 1;
        float r0 = 0.0f, r1 = 0.0f, r2 = 0.0f;
        if ((unsigned)ww < 64u) {
            const float* base = xin + ((size_t)b * 4096 + h * 64 + ww) * 192 + d;
            if (h > 0)  r0 = base[-64 * 192];
            r1 = base[0];
            if (h < 63) r2 = base[64 * 192];
        }
        #pragma unroll
        for (int dd2 = 0; dd2 < 3; ++dd2) {
            int o = jj - 2 + dd2;
            int cj = 2 - dd2;
            if (o >= 0 && o < 8) {
                acc[o] = fmaf(r0, wr[0][cj], acc[o]);
                acc[o] = fmaf(r1, wr[1][cj], acc[o]);
                acc[o] = fmaf(r2, wr[2][cj], acc[o]);
            }
        }
    }
    #pragma unroll
    for (int o = 0; o < 8; ++o) {
        int w = w0 + o;
        int kq = (h & 1) ? ((w & 1) ? 3 : 1) : ((w & 1) ? 2 : 0);
        int l = (kq & 1) ? ((w >> 1) * 32 + (h >> 1))
                         : ((h >> 1) * 32 + (w >> 1));
        xg[((size_t)(b * 4 + kq) * 1024 + l) * 192 + d] = silu_f(acc[o]);
    }
}

// x_dbl GEMM once: per (bk, 16-l tile), 38 rows -> dtr/Bm/Cm.
__global__ __launch_bounds__(192) void k_xdbl(
        const float* __restrict__ xg, const float* __restrict__ xpw,
        float* __restrict__ dtr, float* __restrict__ Bm, float* __restrict__ Cm) {
    __shared__ float sU[16 * USTRIDE];
    int bk = blockIdx.x >> 6;
    int tile = blockIdx.x & 63;
    int k = bk & 3;
    int t = threadIdx.x;
    int lbase = bk * 1024 + tile * 16;
    const float4* usrc = (const float4*)(xg + (size_t)lbase * 192);
    for (int i = t; i < 16 * 48; i += 192) {
        int l = i / 48, c4 = i - l * 48;
        *(float4*)&sU[l * USTRIDE + c4 * 4] = usrc[i];
    }
    __syncthreads();
    int l = t & 15, cgp = t >> 4;
    float acc[4] = {0.f, 0.f, 0.f, 0.f};
    int c3 = (cgp < 2) ? (cgp + 36) : cgp;
    const float* wb = xpw + (size_t)k * 38 * 192;
    for (int qv = 0; qv < 48; ++qv) {
        float4 xv = *(const float4*)&sU[l * USTRIDE + qv * 4];
        float4 w0 = *(const float4*)&wb[(cgp +  0) * 192 + qv * 4];
        float4 w1 = *(const float4*)&wb[(cgp + 12) * 192 + qv * 4];
        float4 w2 = *(const float4*)&wb[(cgp + 24) * 192 + qv * 4];
        float4 w3 = *(const float4*)&wb[(size_t)c3 * 192 + qv * 4];
        acc[0] = fmaf(xv.x, w0.x, fmaf(xv.y, w0.y, fmaf(xv.z, w0.z, fmaf(xv.w, w0.w, acc[0]))));
        acc[1] = fmaf(xv.x, w1.x, fmaf(xv.y, w1.y, fmaf(xv.z, w1.z, fmaf(xv.w, w1.w, acc[1]))));
        acc[2] = fmaf(xv.x, w2.x, fmaf(xv.y, w2.y, fmaf(xv.z, w2.z, fmaf(xv.w, w2.w, acc[2]))));
        acc[3] = fmaf(xv.x, w3.x, fmaf(xv.y, w3.y, fmaf(xv.z, w3.z, fmaf(xv.w, w3.w, acc[3]))));
    }
    int bkl = lbase + l;
    #pragma unroll
    for (int j = 0; j < 4; ++j) {
        int c = cgp + 12 * j;
        if (j == 3) { if (cgp >= 2) break; c = cgp + 36; }
        float v = acc[j];
        if (c < 6)       dtr[(size_t)bkl * 6 + c] = v;
        else if (c < 22) Bm[(size_t)bkl * 16 + (c - 6)] = v;
        else             Cm[(size_t)bkl * 16 + (c - 22)] = v;
    }
}

// Pass 1: local scan (h_in=0). Emits y_local (incl. u*D) to yout, Q (bf16), S.
__global__ __launch_bounds__(192) void k_scan1y(
        const float* __restrict__ xg, const float* __restrict__ dtr,
        const float* __restrict__ Bm, const float* __restrict__ Cm,
        const float* __restrict__ A_logs, const float* __restrict__ dtw,
        const float* __restrict__ dtb, const float* __restrict__ Ds,
        float* __restrict__ Sbuf, unsigned short* __restrict__ Qb,
        float* __restrict__ yout) {
    __shared__ float sU[CHUNK * USTRIDE];
    __shared__ float sB[CHUNK * 16];
    __shared__ float sC[CHUNK * 16];
    int bk = blockIdx.x >> 6;
    int ch = blockIdx.x & 63;
    int k = bk & 3;
    int d = threadIdx.x;
    int lbase = bk * 1024 + ch * CHUNK;
    const float4* usrc = (const float4*)(xg + (size_t)lbase * 192);
    for (int i = d; i < CHUNK * 48; i += 192) {
        int l = i / 48, c4 = i - l * 48;
        *(float4*)&sU[l * USTRIDE + c4 * 4] = usrc[i];
    }
    for (int i = d; i < CHUNK * 16; i += 192) {
        sB[i] = Bm[(size_t)lbase * 16 + i];
        sC[i] = Cm[(size_t)lbase * 16 + i];
    }
    float A[16];
    #pragma unroll
    for (int n = 0; n < 16; ++n) A[n] = -__expf(A_logs[(k * 192 + d) * 16 + n]);
    float A0 = A[0];
    bool geo = true;                 // A[n] == (n+1)*A[0] (geometric ladder)?
    #pragma unroll
    for (int n = 1; n < 16; ++n)
        geo = geo && (fabsf(A[n] - (float)(n + 1) * A0) <= 1e-4f * fabsf(A[n]));
    float wp[6];
    #pragma unroll
    for (int q = 0; q < 6; ++q) wp[q] = dtw[(k * 192 + d) * 6 + q];
    float bias = dtb[k * 192 + d];
    float Dp = Ds[k * 192 + d];
    __syncthreads();
    float h[16];
    #pragma unroll
    for (int n = 0; n < 16; ++n) h[n] = 0.0f;
    float S = 0.0f;
    for (int l = 0; l < CHUNK; ++l) {
        const float* r = dtr + (size_t)(lbase + l) * 6;   // wave-uniform
        float a = bias;
        #pragma unroll
        for (int q = 0; q < 6; ++q) a = fmaf(wp[q], r[q], a);
        float dlt = softplus_f(a);
        S += dlt;
        float u = sU[l * USTRIDE + d];
        float du = dlt * u;
        float y = 0.0f;
        if (geo) {
            float e1 = __expf(dlt * A0);
            float e = e1;
            #pragma unroll
            for (int n = 0; n < 16; ++n) {
                h[n] = fmaf(e, h[n], du * sB[l * 16 + n]);
                y = fmaf(h[n], sC[l * 16 + n], y);
                e *= e1;
            }
        } else {
            #pragma unroll
            for (int n = 0; n < 16; ++n) {
                float e = __expf(dlt * A[n]);
                h[n] = fmaf(e, h[n], du * sB[l * 16 + n]);
                y = fmaf(h[n], sC[l * 16 + n], y);
            }
        }
        yout[(size_t)(lbase + l) * 192 + d] = fmaf(u, Dp, y);
    }
    Sbuf[(size_t)ch * SSTRIDE + bk * 192 + d] = S;
    size_t base = (size_t)ch * NSTATES + bk * (192 * 16);
    #pragma unroll
    for (int n = 0; n < 16; ++n)
        Qb[base + n * 192 + d] = f2bf(h[n]);
}

// Pass 2: prefix over chunks; P = exp(A*S). 4x-batched independent loads.
// Hst[c] = h at start of chunk c (fp32).
__global__ __launch_bounds__(256) void k_scan2(
        const float* __restrict__ Sbuf, const float* __restrict__ A_logs,
        const unsigned short* __restrict__ Qb, float* __restrict__ Hst) {
    int s = blockIdx.x * 256 + threadIdx.x;   // 0..NSTATES-1
    int bk = s / 3072;                         // 3072 = 16*192
    int rem = s - bk * 3072;
    int n = rem / 192;
    int d = rem - n * 192;
    int k = bk & 3;
    float A = -__expf(A_logs[(k * 192 + d) * 16 + n]);
    int sb = bk * 192 + d;
    float h = 0.0f;
    for (int c0 = 0; c0 < NCH; c0 += 4) {
        float S0 = Sbuf[(size_t)(c0 + 0) * SSTRIDE + sb];
        float S1 = Sbuf[(size_t)(c0 + 1) * SSTRIDE + sb];
        float S2 = Sbuf[(size_t)(c0 + 2) * SSTRIDE + sb];
        float S3 = Sbuf[(size_t)(c0 + 3) * SSTRIDE + sb];
        float q0 = bf2f(Qb[(size_t)(c0 + 0) * NSTATES + s]);
        float q1 = bf2f(Qb[(size_t)(c0 + 1) * NSTATES + s]);
        float q2 = bf2f(Qb[(size_t)(c0 + 2) * NSTATES + s]);
        float q3 = bf2f(Qb[(size_t)(c0 + 3) * NSTATES + s]);
        float p0 = __expf(A * S0);
        float p1 = __expf(A * S1);
        float p2 = __expf(A * S2);
        float p3 = __expf(A * S3);
        Hst[(size_t)(c0 + 0) * NSTATES + s] = h;  h = fmaf(p0, h, q0);
        Hst[(size_t)(c0 + 1) * NSTATES + s] = h;  h = fmaf(p1, h, q1);
        Hst[(size_t)(c0 + 2) * NSTATES + s] = h;  h = fmaf(p2, h, q2);
        Hst[(size_t)(c0 + 3) * NSTATES + s] = h;  h = fmaf(p3, h, q3);
    }
}

// Pass 3: chain-free correction. yout[l,d] += sum_n C[l,n]*exp(A[n]*S_l)*h0[n].
// Only serial dependency is S += dlt. ch==0 blocks exit (h0=0).
__global__ __launch_bounds__(192) void k_scan3c(
        const float* __restrict__ dtr, const float* __restrict__ Cm,
        const float* __restrict__ A_logs, const float* __restrict__ dtw,
        const float* __restrict__ dtb, const float* __restrict__ Hst,
        float* __restrict__ yout) {
    __shared__ float sC[CHUNK * 16];
    int bk = blockIdx.x >> 6;
    int ch = blockIdx.x & 63;
    if (ch == 0) return;              // h0 == 0, no correction
    int k = bk & 3;
    int d = threadIdx.x;
    int lbase = bk * 1024 + ch * CHUNK;
    for (int i = d; i < CHUNK * 16; i += 192)
        sC[i] = Cm[(size_t)lbase * 16 + i];
    float A[16];
    #pragma unroll
    for (int n = 0; n < 16; ++n) A[n] = -__expf(A_logs[(k * 192 + d) * 16 + n]);
    float A0 = A[0];
    bool geo = true;
    #pragma unroll
    for (int n = 1; n < 16; ++n)
        geo = geo && (fabsf(A[n] - (float)(n + 1) * A0) <= 1e-4f * fabsf(A[n]));
    float wp[6];
    #pragma unroll
    for (int q = 0; q < 6; ++q) wp[q] = dtw[(k * 192 + d) * 6 + q];
    float bias = dtb[k * 192 + d];
    float h0[16];
    size_t base = (size_t)ch * NSTATES + bk * (192 * 16);
    #pragma unroll
    for (int n = 0; n < 16; ++n) h0[n] = Hst[base + n * 192 + d];
    __syncthreads();
    float S = 0.0f;
    for (int l = 0; l < CHUNK; ++l) {
        const float* r = dtr + (size_t)(lbase + l) * 6;   // wave-uniform
        float a = bias;
        #pragma unroll
        for (int q = 0; q < 6; ++q) a = fmaf(wp[q], r[q], a);
        S += softplus_f(a);
        float y = yout[(size_t)(lbase + l) * 192 + d];
        float corr = 0.0f;
        if (geo) {
            float e1 = __expf(A0 * S);
            float e = e1;
            #pragma unroll
            for (int n = 0; n < 16; ++n) {
                corr = fmaf(h0[n] * e, sC[l * 16 + n], corr);
                e *= e1;
            }
        } else {
            #pragma unroll
            for (int n = 0; n < 16; ++n) {
                float e = __expf(A[n] * S);
                corr = fmaf(h0[n] * e, sC[l * 16 + n], corr);
            }
        }
        yout[(size_t)(lbase + l) * 192 + d] = y + corr;
    }
}

// merge + LayerNorm + gate (bf16 z) -> g (bf16, LDS) -> MFMA out GEMM.
__global__ __launch_bounds__(256) void k_lnout(
        const float* __restrict__ yout, const unsigned short* __restrict__ zb,
        const float* __restrict__ lng, const float* __restrict__ lnb,
        const unsigned short* __restrict__ Wo_bf, float* __restrict__ out) {
    __shared__ __align__(16) short sgb[32 * GSTRIDE];
    int p0 = blockIdx.x * 32;
    int t = threadIdx.x;
    int p = t >> 3;                    // pixel 0..31
    int sub = t & 7;                   // 8 threads per pixel, 24 channels each
    int gp = p0 + p;
    int b = gp >> 12;
    int hw = gp & 4095;
    int h = hw >> 6, w = hw & 63;
    int kq = (h & 1) ? ((w & 1) ? 3 : 1) : ((w & 1) ? 2 : 0);
    int l = (kq & 1) ? ((w >> 1) * 32 + (h >> 1))
                     : ((h >> 1) * 32 + (w >> 1));
    const float* yrow = yout + ((size_t)(b * 4 + kq) * 1024 + l) * 192 + sub * 24;
    float4 yv[6];
    float s = 0.0f, s2 = 0.0f;
    #pragma unroll
    for (int j = 0; j < 6; ++j) {
        float4 v = *(const float4*)(yrow + j * 4);
        yv[j] = v;
        s += v.x + v.y + v.z + v.w;
        s2 += v.x * v.x + v.y * v.y + v.z * v.z + v.w * v.w;
    }
    #pragma unroll
    for (int off = 1; off < 8; off <<= 1) {
        s  += __shfl_xor(s, off, 8);
        s2 += __shfl_xor(s2, off, 8);
    }
    float mu = s * (1.0f / 192.0f);
    float var = s2 * (1.0f / 192.0f) - mu * mu;
    float rstd = rsqrtf(var + 1e-5f);
    const unsigned short* zrow = zb + (size_t)gp * 192 + sub * 24;
    short* grow = sgb + p * GSTRIDE + sub * 24;
    #pragma unroll
    for (int j = 0; j < 6; ++j) {
        ushort4v zv4 = *(const ushort4v*)(zrow + j * 4);
        float4 gv = *(const float4*)(lng + sub * 24 + j * 4);
        float4 bv = *(const float4*)(lnb + sub * 24 + j * 4);
        short4v sv;
        sv.x = (short)f2bf(((yv[j].x - mu) * rstd * gv.x + bv.x) * bf2f(zv4.x));
        sv.y = (short)f2bf(((yv[j].y - mu) * rstd * gv.y + bv.y) * bf2f(zv4.y));
        sv.z = (short)f2bf(((yv[j].z - mu) * rstd * gv.z + bv.z) * bf2f(zv4.z));
        sv.w = (short)f2bf(((yv[j].w - mu) * rstd * gv.w + bv.w) * bf2f(zv4.w));
        *(short4v*)(grow + j * 4) = sv;
    }
    __syncthreads();
    int wv = t >> 6;
    int lane = t & 63;
    int m = lane & 15, quad = lane >> 4;
    int mt = wv >> 1;
    int nb = (wv & 1) * 3;
    const short* wob = (const short*)Wo_bf;
    short8 a[6];
    #pragma unroll
    for (int kk = 0; kk < 6; ++kk)
        a[kk] = *(const short8*)(sgb + (mt * 16 + m) * GSTRIDE + kk * 32 + quad * 8);
    #pragma unroll
    for (int i = 0; i < 3; ++i) {
        int n0 = (nb + i) * 16;
        f32x4 acc = {0.f, 0.f, 0.f, 0.f};
        #pragma unroll
        for (int kk = 0; kk < 6; ++kk) {
            short8 bfr = *(const short8*)(wob + (size_t)(n0 + m) * 192 + kk * 32 + quad * 8);
            acc = __builtin_amdgcn_mfma_f32_16x16x32_bf16(a[kk], bfr, acc, 0, 0, 0);
        }
        #pragma unroll
        for (int r = 0; r < 4; ++r) {
            int pp = p0 + mt * 16 + quad * 4 + r;
            out[(size_t)pp * 96 + n0 + m] = acc[r];
        }
    }
}

extern "C" void kernel_launch(void* const* d_in, const int* in_sizes, int n_in,
                              void* d_out, int out_size, void* d_ws, size_t ws_size,
                              hipStream_t stream) {
    const float* x    = (const float*)d_in[0];
    const float* W_in = (const float*)d_in[1];
    const float* cw   = (const float*)d_in[2];
    const float* cb   = (const float*)d_in[3];
    const float* xpw  = (const float*)d_in[4];
    const float* dtw  = (const float*)d_in[5];
    const float* dtb  = (const float*)d_in[6];
    const float* Alog = (const float*)d_in[7];
    const float* Ds   = (const float*)d_in[8];
    const float* lng  = (const float*)d_in[9];
    const float* lnb  = (const float*)d_in[10];
    const float* Wout = (const float*)d_in[11];
    float* out = (float*)d_out;

    float* ws = (float*)d_ws;
    size_t off = 0;
    unsigned short* Wi_hi = (unsigned short*)(ws + off); off += 384 * 96 / 2;
    unsigned short* Wi_lo = (unsigned short*)(ws + off); off += 384 * 96 / 2;
    unsigned short* Wo_bf = (unsigned short*)(ws + off); off += 96 * DINNER / 2;
    float* xin   = ws + off; off += (size_t)NPIX * 192;
    unsigned short* zb = (unsigned short*)(ws + off); off += (size_t)NPIX * 192 / 2;
    float* xg    = ws + off; off += (size_t)NPIX * 192;
    float* dtrb  = ws + off; off += (size_t)NBK * LP * 6;
    float* Bm    = ws + off; off += (size_t)NBK * LP * 16;
    float* Cm    = ws + off; off += (size_t)NBK * LP * 16;
    float* Sbuf  = ws + off; off += (size_t)NCH * SSTRIDE;
    unsigned short* Qb = (unsigned short*)(ws + off); off += (size_t)NCH * NSTATES / 2;
    float* Hst   = ws + off; off += (size_t)NCH * NSTATES;
    float* yout  = ws + off; off += (size_t)NBK * LP * 192;

    hipLaunchKernelGGL(k_castW, dim3(144), dim3(256), 0, stream,
                       W_in, Wout, Wi_hi, Wi_lo, Wo_bf);
    hipLaunchKernelGGL(k_inproj3, dim3(NPIX / 16), dim3(256), 0, stream,
                       x, Wi_hi, Wi_lo, xin, zb);
    hipLaunchKernelGGL(k_conv8, dim3(NPIX / 8), dim3(192), 0, stream,
                       xin, cw, cb, xg);
    hipLaunchKernelGGL(k_xdbl, dim3(NBK * 64), dim3(192), 0, stream,
                       xg, xpw, dtrb, Bm, Cm);
    hipLaunchKernelGGL(k_scan1y, dim3(NBK * NCH), dim3(192), 0, stream,
                       xg, dtrb, Bm, Cm, Alog, dtw, dtb, Ds, Sbuf, Qb, yout);
    hipLaunchKernelGGL(k_scan2, dim3(NSTATES / 256), dim3(256), 0, stream,
                       Sbuf, Alog, Qb, Hst);
    hipLaunchKernelGGL(k_scan3c, dim3(NBK * NCH), dim3(192), 0, stream,
                       dtrb, Cm, Alog, dtw, dtb, Hst, yout);
    hipLaunchKernelGGL(k_lnout, dim3(NPIX / 32), dim3(256), 0, stream,
                       yout, zb, lng, lnb, Wo_bf, out);
}

// Round 15
// 158.580 us; speedup vs baseline: 1.1009x; 1.0853x over previous
//
#include <hip/hip_runtime.h>
#include <math.h>

// SS2D (VMamba v2) forward — MI355X gfx950.
// fp32 scan core; MFMA bf16x3-split in-proj AND x_dbl GEMM; MFMA bf16 out-proj.
//
// Pipeline (8 dispatches):
//  k_castW   : W_in -> (hi,lo); xpw -> (hi,lo, 48-row padded); W_out -> bf16
//  k_inproj3 : xz = x @ W_in^T via bf16x3 MFMA; A-split staged ONCE in LDS
//  k_conv8   : depthwise 3x3 SAME + bias + silu -> xg (scan order)
//  k_xdbl    : x_dbl via bf16x3 MFMA (u-tile split in LDS) -> dtr/Bm/Cm
//  k_scan1y  : local scan (h_in=0) -> y_local to yout, Q (bf16), S
//  k_scan2   : prefix over 64 chunks (4x-batched); Hst = h at chunk start
//  k_scan3c  : chain-free correction: yout += C·(exp(A·S_l) ⊙ h0)
//  k_lnout   : merge + LayerNorm + gate(bf16 z) -> bf16 LDS -> MFMA out GEMM

#define DINNER 192
#define NSTATE 16
#define KDIR 4
#define BATCH 4
#define NPIX (BATCH * 64 * 64)          // 16384
#define LP 1024
#define NCH 64                          // scan chunks
#define CHUNK 16                        // LP / NCH
#define NBK (BATCH * KDIR)              // 16
#define NSTATES (NBK * DINNER * NSTATE) // 49152
#define SSTRIDE (NBK * DINNER)          // 3072 floats of S per chunk
#define USTRIDE 196                     // scan sU row stride (floats)
#define GSTRIDE 200                     // lnout bf16 g LDS stride (shorts)
#define ASTRIDE 104                     // inproj LDS A stride (shorts, 96 padded)
#define XSTRIDE 200                     // xdbl LDS A stride (shorts, 192 padded)

typedef __attribute__((ext_vector_type(8))) short short8;
typedef __attribute__((ext_vector_type(4))) short short4v;
typedef __attribute__((ext_vector_type(4))) unsigned short ushort4v;
typedef __attribute__((ext_vector_type(4))) float f32x4;

__device__ __forceinline__ float silu_f(float x) {
    return x / (1.0f + __expf(-x));
}
__device__ __forceinline__ float softplus_f(float a) {
    return (a > 20.0f) ? a : __logf(1.0f + __expf(a));
}
__device__ __forceinline__ unsigned short f2bf(float f) {
    unsigned u = __float_as_uint(f);
    unsigned r = (u + 0x7FFFu + ((u >> 16) & 1u)) >> 16;
    return (unsigned short)r;
}
__device__ __forceinline__ float bf2f(unsigned short h) {
    return __uint_as_float(((unsigned)h) << 16);
}

// Weights: W_in hi/lo split; xpw hi/lo split into 48-row padded layout
// (rows 38..47 zero); W_out bf16 cast.
__global__ __launch_bounds__(256) void k_castW(
        const float* __restrict__ W_in, const float* __restrict__ xpw,
        const float* __restrict__ W_out,
        unsigned short* __restrict__ Wi_hi, unsigned short* __restrict__ Wi_lo,
        unsigned short* __restrict__ Xp_hi, unsigned short* __restrict__ Xp_lo,
        unsigned short* __restrict__ Wo_bf) {
    int i = blockIdx.x * 256 + threadIdx.x;
    if (i < 384 * 96) {
        float v = W_in[i];
        unsigned short h = f2bf(v);
        Wi_hi[i] = h;
        Wi_lo[i] = f2bf(v - bf2f(h));
    }
    if (i < 4 * 48 * 192) {           // padded xpw split
        int kk = i / (48 * 192);
        int rem = i - kk * (48 * 192);
        int c = rem / 192;
        int j = rem - c * 192;
        float v = (c < 38) ? xpw[((size_t)kk * 38 + c) * 192 + j] : 0.0f;
        unsigned short h = f2bf(v);
        Xp_hi[i] = h;
        Xp_lo[i] = f2bf(v - bf2f(h));
    }
    if (i < 96 * DINNER) Wo_bf[i] = f2bf(W_out[i]);
}

// MFMA in-proj (bf16x3 split); x split staged ONCE in LDS (shared by 4 waves).
__global__ __launch_bounds__(256) void k_inproj3(
        const float* __restrict__ x,
        const unsigned short* __restrict__ Wi_hi,
        const unsigned short* __restrict__ Wi_lo,
        float* __restrict__ xin, unsigned short* __restrict__ zb) {
    __shared__ __align__(16) short sAh[16 * ASTRIDE];
    __shared__ __align__(16) short sAl[16 * ASTRIDE];
    int p0 = blockIdx.x * 16;
    int t = threadIdx.x;
    const float4* xs = (const float4*)(x + (size_t)p0 * 96);
    for (int i = t; i < 384; i += 256) {     // 16*96 floats = 384 float4
        float4 v = xs[i];
        int f = i * 4;
        int row = f / 96, col = f - row * 96;
        short4v hi, lo;
        unsigned short hb;
        hb = f2bf(v.x); hi.x = (short)hb; lo.x = (short)f2bf(v.x - bf2f(hb));
        hb = f2bf(v.y); hi.y = (short)hb; lo.y = (short)f2bf(v.y - bf2f(hb));
        hb = f2bf(v.z); hi.z = (short)hb; lo.z = (short)f2bf(v.z - bf2f(hb));
        hb = f2bf(v.w); hi.w = (short)hb; lo.w = (short)f2bf(v.w - bf2f(hb));
        *(short4v*)&sAh[row * ASTRIDE + col] = hi;
        *(short4v*)&sAl[row * ASTRIDE + col] = lo;
    }
    __syncthreads();
    int w = t >> 6;
    int lane = t & 63;
    int m = lane & 15, quad = lane >> 4;
    const short* wh = (const short*)Wi_hi;
    const short* wl = (const short*)Wi_lo;
    short8 ah[3], al[3];
    #pragma unroll
    for (int c = 0; c < 3; ++c) {
        ah[c] = *(const short8*)&sAh[m * ASTRIDE + c * 32 + quad * 8];
        al[c] = *(const short8*)&sAl[m * ASTRIDE + c * 32 + quad * 8];
    }
    #pragma unroll
    for (int i = 0; i < 6; ++i) {
        int e0 = (w * 6 + i) * 16;
        f32x4 acc = {0.f, 0.f, 0.f, 0.f};
        #pragma unroll
        for (int c = 0; c < 3; ++c) {
            size_t o = (size_t)(e0 + m) * 96 + c * 32 + quad * 8;
            short8 bh = *(const short8*)(wh + o);
            short8 bl = *(const short8*)(wl + o);
            acc = __builtin_amdgcn_mfma_f32_16x16x32_bf16(ah[c], bl, acc, 0, 0, 0);
            acc = __builtin_amdgcn_mfma_f32_16x16x32_bf16(al[c], bh, acc, 0, 0, 0);
            acc = __builtin_amdgcn_mfma_f32_16x16x32_bf16(ah[c], bh, acc, 0, 0, 0);
        }
        int e = e0 + m;
        #pragma unroll
        for (int r = 0; r < 4; ++r) {
            int p = p0 + quad * 4 + r;
            if (e < 192) xin[(size_t)p * 192 + e] = acc[r];
            else         zb[(size_t)p * 192 + (e - 192)] = f2bf(silu_f(acc[r]));
        }
    }
}

// depthwise 3x3, 8 consecutive pixels of one row per block; sliding-window loads.
__global__ __launch_bounds__(192) void k_conv8(
        const float* __restrict__ xin, const float* __restrict__ cw,
        const float* __restrict__ cb, float* __restrict__ xg) {
    int blk = blockIdx.x;             // 2048 = 4 b * 64 h * 8 wchunks
    int b = blk >> 9;
    int rem = blk & 511;
    int h = rem >> 3;
    int w0 = (rem & 7) * 8;
    int d = threadIdx.x;
    float wr[3][3];
    #pragma unroll
    for (int i = 0; i < 3; ++i)
        #pragma unroll
        for (int j = 0; j < 3; ++j) wr[i][j] = cw[d * 9 + i * 3 + j];
    float bias = cb[d];
    float acc[8];
    #pragma unroll
    for (int o = 0; o < 8; ++o) acc[o] = bias;
    #pragma unroll
    for (int jj = 0; jj < 10; ++jj) {
        int ww = w0 + jj - 1;
        float r0 = 0.0f, r1 = 0.0f, r2 = 0.0f;
        if ((unsigned)ww < 64u) {
            const float* base = xin + ((size_t)b * 4096 + h * 64 + ww) * 192 + d;
            if (h > 0)  r0 = base[-64 * 192];
            r1 = base[0];
            if (h < 63) r2 = base[64 * 192];
        }
        #pragma unroll
        for (int dd2 = 0; dd2 < 3; ++dd2) {
            int o = jj - 2 + dd2;
            int cj = 2 - dd2;
            if (o >= 0 && o < 8) {
                acc[o] = fmaf(r0, wr[0][cj], acc[o]);
                acc[o] = fmaf(r1, wr[1][cj], acc[o]);
                acc[o] = fmaf(r2, wr[2][cj], acc[o]);
            }
        }
    }
    #pragma unroll
    for (int o = 0; o < 8; ++o) {
        int w = w0 + o;
        int kq = (h & 1) ? ((w & 1) ? 3 : 1) : ((w & 1) ? 2 : 0);
        int l = (kq & 1) ? ((w >> 1) * 32 + (h >> 1))
                         : ((h >> 1) * 32 + (w >> 1));
        xg[((size_t)(b * 4 + kq) * 1024 + l) * 192 + d] = silu_f(acc[o]);
    }
}

// x_dbl via bf16x3 MFMA: per (bk, 16-l tile). 3 waves = 3 N-tiles (48 c-rows,
// 38 valid). A = u-tile split in LDS; B = padded Xp hi/lo (row-major).
__global__ __launch_bounds__(192) void k_xdbl(
        const float* __restrict__ xg,
        const unsigned short* __restrict__ Xp_hi,
        const unsigned short* __restrict__ Xp_lo,
        float* __restrict__ dtr, float* __restrict__ Bm, float* __restrict__ Cm) {
    __shared__ __align__(16) short sAh[16 * XSTRIDE];
    __shared__ __align__(16) short sAl[16 * XSTRIDE];
    int bk = blockIdx.x >> 6;
    int tile = blockIdx.x & 63;
    int k = bk & 3;
    int t = threadIdx.x;
    int lbase = bk * 1024 + tile * 16;
    const float4* us = (const float4*)(xg + (size_t)lbase * 192);
    for (int i = t; i < 768; i += 192) {     // 16*192 floats = 768 float4
        float4 v = us[i];
        int f = i * 4;
        int row = f / 192, col = f - row * 192;
        short4v hi, lo;
        unsigned short hb;
        hb = f2bf(v.x); hi.x = (short)hb; lo.x = (short)f2bf(v.x - bf2f(hb));
        hb = f2bf(v.y); hi.y = (short)hb; lo.y = (short)f2bf(v.y - bf2f(hb));
        hb = f2bf(v.z); hi.z = (short)hb; lo.z = (short)f2bf(v.z - bf2f(hb));
        hb = f2bf(v.w); hi.w = (short)hb; lo.w = (short)f2bf(v.w - bf2f(hb));
        *(short4v*)&sAh[row * XSTRIDE + col] = hi;
        *(short4v*)&sAl[row * XSTRIDE + col] = lo;
    }
    __syncthreads();
    int wv = t >> 6;                  // N-tile 0..2
    int lane = t & 63;
    int m = lane & 15, quad = lane >> 4;
    const short* bh16 = (const short*)Xp_hi;
    const short* bl16 = (const short*)Xp_lo;
    int n0 = wv * 16;
    size_t brow = ((size_t)k * 48 + n0 + m) * 192;
    f32x4 acc = {0.f, 0.f, 0.f, 0.f};
    #pragma unroll
    for (int c = 0; c < 6; ++c) {
        short8 ah = *(const short8*)&sAh[m * XSTRIDE + c * 32 + quad * 8];
        short8 al = *(const short8*)&sAl[m * XSTRIDE + c * 32 + quad * 8];
        short8 bh = *(const short8*)(bh16 + brow + c * 32 + quad * 8);
        short8 bl = *(const short8*)(bl16 + brow + c * 32 + quad * 8);
        acc = __builtin_amdgcn_mfma_f32_16x16x32_bf16(ah, bl, acc, 0, 0, 0);
        acc = __builtin_amdgcn_mfma_f32_16x16x32_bf16(al, bh, acc, 0, 0, 0);
        acc = __builtin_amdgcn_mfma_f32_16x16x32_bf16(ah, bh, acc, 0, 0, 0);
    }
    int c = n0 + m;                   // output c-row
    #pragma unroll
    for (int r = 0; r < 4; ++r) {
        int bkl = lbase + quad * 4 + r;
        float v = acc[r];
        if (c < 6)       dtr[(size_t)bkl * 6 + c] = v;
        else if (c < 22) Bm[(size_t)bkl * 16 + (c - 6)] = v;
        else if (c < 38) Cm[(size_t)bkl * 16 + (c - 22)] = v;
    }
}

// Pass 1: local scan (h_in=0). Emits y_local (incl. u*D) to yout, Q (bf16), S.
__global__ __launch_bounds__(192) void k_scan1y(
        const float* __restrict__ xg, const float* __restrict__ dtr,
        const float* __restrict__ Bm, const float* __restrict__ Cm,
        const float* __restrict__ A_logs, const float* __restrict__ dtw,
        const float* __restrict__ dtb, const float* __restrict__ Ds,
        float* __restrict__ Sbuf, unsigned short* __restrict__ Qb,
        float* __restrict__ yout) {
    __shared__ float sU[CHUNK * USTRIDE];
    __shared__ float sB[CHUNK * 16];
    __shared__ float sC[CHUNK * 16];
    int bk = blockIdx.x >> 6;
    int ch = blockIdx.x & 63;
    int k = bk & 3;
    int d = threadIdx.x;
    int lbase = bk * 1024 + ch * CHUNK;
    const float4* usrc = (const float4*)(xg + (size_t)lbase * 192);
    for (int i = d; i < CHUNK * 48; i += 192) {
        int l = i / 48, c4 = i - l * 48;
        *(float4*)&sU[l * USTRIDE + c4 * 4] = usrc[i];
    }
    for (int i = d; i < CHUNK * 16; i += 192) {
        sB[i] = Bm[(size_t)lbase * 16 + i];
        sC[i] = Cm[(size_t)lbase * 16 + i];
    }
    float A[16];
    #pragma unroll
    for (int n = 0; n < 16; ++n) A[n] = -__expf(A_logs[(k * 192 + d) * 16 + n]);
    float A0 = A[0];
    bool geo = true;                 // A[n] == (n+1)*A[0] (geometric ladder)?
    #pragma unroll
    for (int n = 1; n < 16; ++n)
        geo = geo && (fabsf(A[n] - (float)(n + 1) * A0) <= 1e-4f * fabsf(A[n]));
    float wp[6];
    #pragma unroll
    for (int q = 0; q < 6; ++q) wp[q] = dtw[(k * 192 + d) * 6 + q];
    float bias = dtb[k * 192 + d];
    float Dp = Ds[k * 192 + d];
    __syncthreads();
    float h[16];
    #pragma unroll
    for (int n = 0; n < 16; ++n) h[n] = 0.0f;
    float S = 0.0f;
    for (int l = 0; l < CHUNK; ++l) {
        const float* r = dtr + (size_t)(lbase + l) * 6;   // wave-uniform
        float a = bias;
        #pragma unroll
        for (int q = 0; q < 6; ++q) a = fmaf(wp[q], r[q], a);
        float dlt = softplus_f(a);
        S += dlt;
        float u = sU[l * USTRIDE + d];
        float du = dlt * u;
        float y = 0.0f;
        if (geo) {
            float e1 = __expf(dlt * A0);
            float e = e1;
            #pragma unroll
            for (int n = 0; n < 16; ++n) {
                h[n] = fmaf(e, h[n], du * sB[l * 16 + n]);
                y = fmaf(h[n], sC[l * 16 + n], y);
                e *= e1;
            }
        } else {
            #pragma unroll
            for (int n = 0; n < 16; ++n) {
                float e = __expf(dlt * A[n]);
                h[n] = fmaf(e, h[n], du * sB[l * 16 + n]);
                y = fmaf(h[n], sC[l * 16 + n], y);
            }
        }
        yout[(size_t)(lbase + l) * 192 + d] = fmaf(u, Dp, y);
    }
    Sbuf[(size_t)ch * SSTRIDE + bk * 192 + d] = S;
    size_t base = (size_t)ch * NSTATES + bk * (192 * 16);
    #pragma unroll
    for (int n = 0; n < 16; ++n)
        Qb[base + n * 192 + d] = f2bf(h[n]);
}

// Pass 2: prefix over chunks; P = exp(A*S). 4x-batched independent loads.
__global__ __launch_bounds__(256) void k_scan2(
        const float* __restrict__ Sbuf, const float* __restrict__ A_logs,
        const unsigned short* __restrict__ Qb, float* __restrict__ Hst) {
    int s = blockIdx.x * 256 + threadIdx.x;   // 0..NSTATES-1
    int bk = s / 3072;                         // 3072 = 16*192
    int rem = s - bk * 3072;
    int n = rem / 192;
    int d = rem - n * 192;
    int k = bk & 3;
    float A = -__expf(A_logs[(k * 192 + d) * 16 + n]);
    int sb = bk * 192 + d;
    float h = 0.0f;
    for (int c0 = 0; c0 < NCH; c0 += 4) {
        float S0 = Sbuf[(size_t)(c0 + 0) * SSTRIDE + sb];
        float S1 = Sbuf[(size_t)(c0 + 1) * SSTRIDE + sb];
        float S2 = Sbuf[(size_t)(c0 + 2) * SSTRIDE + sb];
        float S3 = Sbuf[(size_t)(c0 + 3) * SSTRIDE + sb];
        float q0 = bf2f(Qb[(size_t)(c0 + 0) * NSTATES + s]);
        float q1 = bf2f(Qb[(size_t)(c0 + 1) * NSTATES + s]);
        float q2 = bf2f(Qb[(size_t)(c0 + 2) * NSTATES + s]);
        float q3 = bf2f(Qb[(size_t)(c0 + 3) * NSTATES + s]);
        float p0 = __expf(A * S0);
        float p1 = __expf(A * S1);
        float p2 = __expf(A * S2);
        float p3 = __expf(A * S3);
        Hst[(size_t)(c0 + 0) * NSTATES + s] = h;  h = fmaf(p0, h, q0);
        Hst[(size_t)(c0 + 1) * NSTATES + s] = h;  h = fmaf(p1, h, q1);
        Hst[(size_t)(c0 + 2) * NSTATES + s] = h;  h = fmaf(p2, h, q2);
        Hst[(size_t)(c0 + 3) * NSTATES + s] = h;  h = fmaf(p3, h, q3);
    }
}

// Pass 3: chain-free correction. yout[l,d] += sum_n C[l,n]*exp(A[n]*S_l)*h0[n].
__global__ __launch_bounds__(192) void k_scan3c(
        const float* __restrict__ dtr, const float* __restrict__ Cm,
        const float* __restrict__ A_logs, const float* __restrict__ dtw,
        const float* __restrict__ dtb, const float* __restrict__ Hst,
        float* __restrict__ yout) {
    __shared__ float sC[CHUNK * 16];
    int bk = blockIdx.x >> 6;
    int ch = blockIdx.x & 63;
    if (ch == 0) return;              // h0 == 0, no correction
    int k = bk & 3;
    int d = threadIdx.x;
    int lbase = bk * 1024 + ch * CHUNK;
    for (int i = d; i < CHUNK * 16; i += 192)
        sC[i] = Cm[(size_t)lbase * 16 + i];
    float A[16];
    #pragma unroll
    for (int n = 0; n < 16; ++n) A[n] = -__expf(A_logs[(k * 192 + d) * 16 + n]);
    float A0 = A[0];
    bool geo = true;
    #pragma unroll
    for (int n = 1; n < 16; ++n)
        geo = geo && (fabsf(A[n] - (float)(n + 1) * A0) <= 1e-4f * fabsf(A[n]));
    float wp[6];
    #pragma unroll
    for (int q = 0; q < 6; ++q) wp[q] = dtw[(k * 192 + d) * 6 + q];
    float bias = dtb[k * 192 + d];
    float h0[16];
    size_t base = (size_t)ch * NSTATES + bk * (192 * 16);
    #pragma unroll
    for (int n = 0; n < 16; ++n) h0[n] = Hst[base + n * 192 + d];
    __syncthreads();
    float S = 0.0f;
    for (int l = 0; l < CHUNK; ++l) {
        const float* r = dtr + (size_t)(lbase + l) * 6;   // wave-uniform
        float a = bias;
        #pragma unroll
        for (int q = 0; q < 6; ++q) a = fmaf(wp[q], r[q], a);
        S += softplus_f(a);
        float y = yout[(size_t)(lbase + l) * 192 + d];
        float corr = 0.0f;
        if (geo) {
            float e1 = __expf(A0 * S);
            float e = e1;
            #pragma unroll
            for (int n = 0; n < 16; ++n) {
                corr = fmaf(h0[n] * e, sC[l * 16 + n], corr);
                e *= e1;
            }
        } else {
            #pragma unroll
            for (int n = 0; n < 16; ++n) {
                float e = __expf(A[n] * S);
                corr = fmaf(h0[n] * e, sC[l * 16 + n], corr);
            }
        }
        yout[(size_t)(lbase + l) * 192 + d] = y + corr;
    }
}

// merge + LayerNorm + gate (bf16 z) -> g (bf16, LDS) -> MFMA out GEMM.
__global__ __launch_bounds__(256) void k_lnout(
        const float* __restrict__ yout, const unsigned short* __restrict__ zb,
        const float* __restrict__ lng, const float* __restrict__ lnb,
        const unsigned short* __restrict__ Wo_bf, float* __restrict__ out) {
    __shared__ __align__(16) short sgb[32 * GSTRIDE];
    int p0 = blockIdx.x * 32;
    int t = threadIdx.x;
    int p = t >> 3;                    // pixel 0..31
    int sub = t & 7;                   // 8 threads per pixel, 24 channels each
    int gp = p0 + p;
    int b = gp >> 12;
    int hw = gp & 4095;
    int h = hw >> 6, w = hw & 63;
    int kq = (h & 1) ? ((w & 1) ? 3 : 1) : ((w & 1) ? 2 : 0);
    int l = (kq & 1) ? ((w >> 1) * 32 + (h >> 1))
                     : ((h >> 1) * 32 + (w >> 1));
    const float* yrow = yout + ((size_t)(b * 4 + kq) * 1024 + l) * 192 + sub * 24;
    float4 yv[6];
    float s = 0.0f, s2 = 0.0f;
    #pragma unroll
    for (int j = 0; j < 6; ++j) {
        float4 v = *(const float4*)(yrow + j * 4);
        yv[j] = v;
        s += v.x + v.y + v.z + v.w;
        s2 += v.x * v.x + v.y * v.y + v.z * v.z + v.w * v.w;
    }
    #pragma unroll
    for (int off = 1; off < 8; off <<= 1) {
        s  += __shfl_xor(s, off, 8);
        s2 += __shfl_xor(s2, off, 8);
    }
    float mu = s * (1.0f / 192.0f);
    float var = s2 * (1.0f / 192.0f) - mu * mu;
    float rstd = rsqrtf(var + 1e-5f);
    const unsigned short* zrow = zb + (size_t)gp * 192 + sub * 24;
    short* grow = sgb + p * GSTRIDE + sub * 24;
    #pragma unroll
    for (int j = 0; j < 6; ++j) {
        ushort4v zv4 = *(const ushort4v*)(zrow + j * 4);
        float4 gv = *(const float4*)(lng + sub * 24 + j * 4);
        float4 bv = *(const float4*)(lnb + sub * 24 + j * 4);
        short4v sv;
        sv.x = (short)f2bf(((yv[j].x - mu) * rstd * gv.x + bv.x) * bf2f(zv4.x));
        sv.y = (short)f2bf(((yv[j].y - mu) * rstd * gv.y + bv.y) * bf2f(zv4.y));
        sv.z = (short)f2bf(((yv[j].z - mu) * rstd * gv.z + bv.z) * bf2f(zv4.z));
        sv.w = (short)f2bf(((yv[j].w - mu) * rstd * gv.w + bv.w) * bf2f(zv4.w));
        *(short4v*)(grow + j * 4) = sv;
    }
    __syncthreads();
    int wv = t >> 6;
    int lane = t & 63;
    int m = lane & 15, quad = lane >> 4;
    int mt = wv >> 1;
    int nb = (wv & 1) * 3;
    const short* wob = (const short*)Wo_bf;
    short8 a[6];
    #pragma unroll
    for (int kk = 0; kk < 6; ++kk)
        a[kk] = *(const short8*)(sgb + (mt * 16 + m) * GSTRIDE + kk * 32 + quad * 8);
    #pragma unroll
    for (int i = 0; i < 3; ++i) {
        int n0 = (nb + i) * 16;
        f32x4 acc = {0.f, 0.f, 0.f, 0.f};
        #pragma unroll
        for (int kk = 0; kk < 6; ++kk) {
            short8 bfr = *(const short8*)(wob + (size_t)(n0 + m) * 192 + kk * 32 + quad * 8);
            acc = __builtin_amdgcn_mfma_f32_16x16x32_bf16(a[kk], bfr, acc, 0, 0, 0);
        }
        #pragma unroll
        for (int r = 0; r < 4; ++r) {
            int pp = p0 + mt * 16 + quad * 4 + r;
            out[(size_t)pp * 96 + n0 + m] = acc[r];
        }
    }
}

extern "C" void kernel_launch(void* const* d_in, const int* in_sizes, int n_in,
                              void* d_out, int out_size, void* d_ws, size_t ws_size,
                              hipStream_t stream) {
    const float* x    = (const float*)d_in[0];
    const float* W_in = (const float*)d_in[1];
    const float* cw   = (const float*)d_in[2];
    const float* cb   = (const float*)d_in[3];
    const float* xpw  = (const float*)d_in[4];
    const float* dtw  = (const float*)d_in[5];
    const float* dtb  = (const float*)d_in[6];
    const float* Alog = (const float*)d_in[7];
    const float* Ds   = (const float*)d_in[8];
    const float* lng  = (const float*)d_in[9];
    const float* lnb  = (const float*)d_in[10];
    const float* Wout = (const float*)d_in[11];
    float* out = (float*)d_out;

    float* ws = (float*)d_ws;
    size_t off = 0;
    unsigned short* Wi_hi = (unsigned short*)(ws + off); off += 384 * 96 / 2;
    unsigned short* Wi_lo = (unsigned short*)(ws + off); off += 384 * 96 / 2;
    unsigned short* Xp_hi = (unsigned short*)(ws + off); off += 4 * 48 * 192 / 2;
    unsigned short* Xp_lo = (unsigned short*)(ws + off); off += 4 * 48 * 192 / 2;
    unsigned short* Wo_bf = (unsigned short*)(ws + off); off += 96 * DINNER / 2;
    float* xin   = ws + off; off += (size_t)NPIX * 192;
    unsigned short* zb = (unsigned short*)(ws + off); off += (size_t)NPIX * 192 / 2;
    float* xg    = ws + off; off += (size_t)NPIX * 192;
    float* dtrb  = ws + off; off += (size_t)NBK * LP * 6;
    float* Bm    = ws + off; off += (size_t)NBK * LP * 16;
    float* Cm    = ws + off; off += (size_t)NBK * LP * 16;
    float* Sbuf  = ws + off; off += (size_t)NCH * SSTRIDE;
    unsigned short* Qb = (unsigned short*)(ws + off); off += (size_t)NCH * NSTATES / 2;
    float* Hst   = ws + off; off += (size_t)NCH * NSTATES;
    float* yout  = ws + off; off += (size_t)NBK * LP * 192;

    hipLaunchKernelGGL(k_castW, dim3(144), dim3(256), 0, stream,
                       W_in, xpw, Wout, Wi_hi, Wi_lo, Xp_hi, Xp_lo, Wo_bf);
    hipLaunchKernelGGL(k_inproj3, dim3(NPIX / 16), dim3(256), 0, stream,
                       x, Wi_hi, Wi_lo, xin, zb);
    hipLaunchKernelGGL(k_conv8, dim3(NPIX / 8), dim3(192), 0, stream,
                       xin, cw, cb, xg);
    hipLaunchKernelGGL(k_xdbl, dim3(NBK * 64), dim3(192), 0, stream,
                       xg, Xp_hi, Xp_lo, dtrb, Bm, Cm);
    hipLaunchKernelGGL(k_scan1y, dim3(NBK * NCH), dim3(192), 0, stream,
                       xg, dtrb, Bm, Cm, Alog, dtw, dtb, Ds, Sbuf, Qb, yout);
    hipLaunchKernelGGL(k_scan2, dim3(NSTATES / 256), dim3(256), 0, stream,
                       Sbuf, Alog, Qb, Hst);
    hipLaunchKernelGGL(k_scan3c, dim3(NBK * NCH), dim3(192), 0, stream,
                       dtrb, Cm, Alog, dtw, dtb, Hst, yout);
    hipLaunchKernelGGL(k_lnout, dim3(NPIX / 32), dim3(256), 0, stream,
                       yout, zb, lng, lnb, Wo_bf, out);
}

// Round 16
// 157.998 us; speedup vs baseline: 1.1050x; 1.0037x over previous
//
#include <hip/hip_runtime.h>
#include <math.h>

// SS2D (VMamba v2) forward — MI355X gfx950.
// fp32 scan core; MFMA bf16x3-split in-proj AND x_dbl GEMM; MFMA bf16 out-proj.
//
// Pipeline (8 dispatches):
//  k_castW   : W_in -> (hi,lo); xpw -> (hi,lo, 48-row padded); W_out -> bf16
//  k_inproj3 : xz = x @ W_in^T via bf16x3 MFMA; A-split staged ONCE in LDS
//  k_conv8   : depthwise 3x3 (window preloaded to regs) + bias + silu -> xg
//  k_xdbl    : x_dbl via bf16x3 MFMA (u-tile split in LDS) -> dtr/Bm/Cm
//  k_scan1y  : local scan; delta/exp hoisted out of the serial chain
//  k_scan2   : prefix over 64 chunks (8x-batched); Hst = h at chunk start
//  k_scan3c  : chain-free correction, fully precomputed decays
//  k_lnout   : merge + LayerNorm + gate(bf16 z) -> bf16 LDS -> MFMA out GEMM

#define DINNER 192
#define NSTATE 16
#define KDIR 4
#define BATCH 4
#define NPIX (BATCH * 64 * 64)          // 16384
#define LP 1024
#define NCH 64                          // scan chunks
#define CHUNK 16                        // LP / NCH
#define NBK (BATCH * KDIR)              // 16
#define NSTATES (NBK * DINNER * NSTATE) // 49152
#define SSTRIDE (NBK * DINNER)          // 3072 floats of S per chunk
#define USTRIDE 196                     // scan sU row stride (floats)
#define GSTRIDE 200                     // lnout bf16 g LDS stride (shorts)
#define ASTRIDE 104                     // inproj LDS A stride (shorts, 96 padded)
#define XSTRIDE 200                     // xdbl LDS A stride (shorts, 192 padded)

typedef __attribute__((ext_vector_type(8))) short short8;
typedef __attribute__((ext_vector_type(4))) short short4v;
typedef __attribute__((ext_vector_type(4))) unsigned short ushort4v;
typedef __attribute__((ext_vector_type(4))) float f32x4;

__device__ __forceinline__ float silu_f(float x) {
    return x / (1.0f + __expf(-x));
}
__device__ __forceinline__ float softplus_f(float a) {
    return (a > 20.0f) ? a : __logf(1.0f + __expf(a));
}
__device__ __forceinline__ unsigned short f2bf(float f) {
    unsigned u = __float_as_uint(f);
    unsigned r = (u + 0x7FFFu + ((u >> 16) & 1u)) >> 16;
    return (unsigned short)r;
}
__device__ __forceinline__ float bf2f(unsigned short h) {
    return __uint_as_float(((unsigned)h) << 16);
}

// Weights: W_in hi/lo split; xpw hi/lo split into 48-row padded layout
// (rows 38..47 zero); W_out bf16 cast.
__global__ __launch_bounds__(256) void k_castW(
        const float* __restrict__ W_in, const float* __restrict__ xpw,
        const float* __restrict__ W_out,
        unsigned short* __restrict__ Wi_hi, unsigned short* __restrict__ Wi_lo,
        unsigned short* __restrict__ Xp_hi, unsigned short* __restrict__ Xp_lo,
        unsigned short* __restrict__ Wo_bf) {
    int i = blockIdx.x * 256 + threadIdx.x;
    if (i < 384 * 96) {
        float v = W_in[i];
        unsigned short h = f2bf(v);
        Wi_hi[i] = h;
        Wi_lo[i] = f2bf(v - bf2f(h));
    }
    if (i < 4 * 48 * 192) {           // padded xpw split
        int kk = i / (48 * 192);
        int rem = i - kk * (48 * 192);
        int c = rem / 192;
        int j = rem - c * 192;
        float v = (c < 38) ? xpw[((size_t)kk * 38 + c) * 192 + j] : 0.0f;
        unsigned short h = f2bf(v);
        Xp_hi[i] = h;
        Xp_lo[i] = f2bf(v - bf2f(h));
    }
    if (i < 96 * DINNER) Wo_bf[i] = f2bf(W_out[i]);
}

// MFMA in-proj (bf16x3 split); x split staged ONCE in LDS (shared by 4 waves).
__global__ __launch_bounds__(256) void k_inproj3(
        const float* __restrict__ x,
        const unsigned short* __restrict__ Wi_hi,
        const unsigned short* __restrict__ Wi_lo,
        float* __restrict__ xin, unsigned short* __restrict__ zb) {
    __shared__ __align__(16) short sAh[16 * ASTRIDE];
    __shared__ __align__(16) short sAl[16 * ASTRIDE];
    int p0 = blockIdx.x * 16;
    int t = threadIdx.x;
    const float4* xs = (const float4*)(x + (size_t)p0 * 96);
    for (int i = t; i < 384; i += 256) {     // 16*96 floats = 384 float4
        float4 v = xs[i];
        int f = i * 4;
        int row = f / 96, col = f - row * 96;
        short4v hi, lo;
        unsigned short hb;
        hb = f2bf(v.x); hi.x = (short)hb; lo.x = (short)f2bf(v.x - bf2f(hb));
        hb = f2bf(v.y); hi.y = (short)hb; lo.y = (short)f2bf(v.y - bf2f(hb));
        hb = f2bf(v.z); hi.z = (short)hb; lo.z = (short)f2bf(v.z - bf2f(hb));
        hb = f2bf(v.w); hi.w = (short)hb; lo.w = (short)f2bf(v.w - bf2f(hb));
        *(short4v*)&sAh[row * ASTRIDE + col] = hi;
        *(short4v*)&sAl[row * ASTRIDE + col] = lo;
    }
    __syncthreads();
    int w = t >> 6;
    int lane = t & 63;
    int m = lane & 15, quad = lane >> 4;
    const short* wh = (const short*)Wi_hi;
    const short* wl = (const short*)Wi_lo;
    short8 ah[3], al[3];
    #pragma unroll
    for (int c = 0; c < 3; ++c) {
        ah[c] = *(const short8*)&sAh[m * ASTRIDE + c * 32 + quad * 8];
        al[c] = *(const short8*)&sAl[m * ASTRIDE + c * 32 + quad * 8];
    }
    #pragma unroll
    for (int i = 0; i < 6; ++i) {
        int e0 = (w * 6 + i) * 16;
        f32x4 acc = {0.f, 0.f, 0.f, 0.f};
        #pragma unroll
        for (int c = 0; c < 3; ++c) {
            size_t o = (size_t)(e0 + m) * 96 + c * 32 + quad * 8;
            short8 bh = *(const short8*)(wh + o);
            short8 bl = *(const short8*)(wl + o);
            acc = __builtin_amdgcn_mfma_f32_16x16x32_bf16(ah[c], bl, acc, 0, 0, 0);
            acc = __builtin_amdgcn_mfma_f32_16x16x32_bf16(al[c], bh, acc, 0, 0, 0);
            acc = __builtin_amdgcn_mfma_f32_16x16x32_bf16(ah[c], bh, acc, 0, 0, 0);
        }
        int e = e0 + m;
        #pragma unroll
        for (int r = 0; r < 4; ++r) {
            int p = p0 + quad * 4 + r;
            if (e < 192) xin[(size_t)p * 192 + e] = acc[r];
            else         zb[(size_t)p * 192 + (e - 192)] = f2bf(silu_f(acc[r]));
        }
    }
}

// depthwise 3x3, 8 pixels/block; full 3x10 window preloaded into registers.
__global__ __launch_bounds__(192) void k_conv8(
        const float* __restrict__ xin, const float* __restrict__ cw,
        const float* __restrict__ cb, float* __restrict__ xg) {
    int blk = blockIdx.x;             // 2048 = 4 b * 64 h * 8 wchunks
    int b = blk >> 9;
    int rem = blk & 511;
    int h = rem >> 3;
    int w0 = (rem & 7) * 8;
    int d = threadIdx.x;
    float wr[3][3];
    #pragma unroll
    for (int i = 0; i < 3; ++i)
        #pragma unroll
        for (int j = 0; j < 3; ++j) wr[i][j] = cw[d * 9 + i * 3 + j];
    float bias = cb[d];
    // ---- load phase: all 30 loads issued before any compute ----
    float r0[10], r1[10], r2[10];
    #pragma unroll
    for (int jj = 0; jj < 10; ++jj) {
        int ww = w0 + jj - 1;
        bool inw = (unsigned)ww < 64u;        // block-uniform
        const float* base = xin + ((size_t)b * 4096 + h * 64 + (inw ? ww : 0)) * 192 + d;
        r0[jj] = (inw && h > 0)  ? base[-64 * 192] : 0.0f;
        r1[jj] = inw             ? base[0]         : 0.0f;
        r2[jj] = (inw && h < 63) ? base[64 * 192]  : 0.0f;
    }
    // ---- compute phase ----
    float acc[8];
    #pragma unroll
    for (int o = 0; o < 8; ++o) {
        float a = bias;
        #pragma unroll
        for (int j = 0; j < 3; ++j) {
            a = fmaf(r0[o + j], wr[0][j], a);
            a = fmaf(r1[o + j], wr[1][j], a);
            a = fmaf(r2[o + j], wr[2][j], a);
        }
        acc[o] = a;
    }
    #pragma unroll
    for (int o = 0; o < 8; ++o) {
        int w = w0 + o;
        int kq = (h & 1) ? ((w & 1) ? 3 : 1) : ((w & 1) ? 2 : 0);
        int l = (kq & 1) ? ((w >> 1) * 32 + (h >> 1))
                         : ((h >> 1) * 32 + (w >> 1));
        xg[((size_t)(b * 4 + kq) * 1024 + l) * 192 + d] = silu_f(acc[o]);
    }
}

// x_dbl via bf16x3 MFMA: per (bk, 16-l tile). 3 waves = 3 N-tiles (48 c-rows,
// 38 valid). A = u-tile split in LDS; B = padded Xp hi/lo (row-major).
__global__ __launch_bounds__(192) void k_xdbl(
        const float* __restrict__ xg,
        const unsigned short* __restrict__ Xp_hi,
        const unsigned short* __restrict__ Xp_lo,
        float* __restrict__ dtr, float* __restrict__ Bm, float* __restrict__ Cm) {
    __shared__ __align__(16) short sAh[16 * XSTRIDE];
    __shared__ __align__(16) short sAl[16 * XSTRIDE];
    int bk = blockIdx.x >> 6;
    int tile = blockIdx.x & 63;
    int k = bk & 3;
    int t = threadIdx.x;
    int lbase = bk * 1024 + tile * 16;
    const float4* us = (const float4*)(xg + (size_t)lbase * 192);
    for (int i = t; i < 768; i += 192) {     // 16*192 floats = 768 float4
        float4 v = us[i];
        int f = i * 4;
        int row = f / 192, col = f - row * 192;
        short4v hi, lo;
        unsigned short hb;
        hb = f2bf(v.x); hi.x = (short)hb; lo.x = (short)f2bf(v.x - bf2f(hb));
        hb = f2bf(v.y); hi.y = (short)hb; lo.y = (short)f2bf(v.y - bf2f(hb));
        hb = f2bf(v.z); hi.z = (short)hb; lo.z = (short)f2bf(v.z - bf2f(hb));
        hb = f2bf(v.w); hi.w = (short)hb; lo.w = (short)f2bf(v.w - bf2f(hb));
        *(short4v*)&sAh[row * XSTRIDE + col] = hi;
        *(short4v*)&sAl[row * XSTRIDE + col] = lo;
    }
    __syncthreads();
    int wv = t >> 6;                  // N-tile 0..2
    int lane = t & 63;
    int m = lane & 15, quad = lane >> 4;
    const short* bh16 = (const short*)Xp_hi;
    const short* bl16 = (const short*)Xp_lo;
    int n0 = wv * 16;
    size_t brow = ((size_t)k * 48 + n0 + m) * 192;
    f32x4 acc = {0.f, 0.f, 0.f, 0.f};
    #pragma unroll
    for (int c = 0; c < 6; ++c) {
        short8 ah = *(const short8*)&sAh[m * XSTRIDE + c * 32 + quad * 8];
        short8 al = *(const short8*)&sAl[m * XSTRIDE + c * 32 + quad * 8];
        short8 bh = *(const short8*)(bh16 + brow + c * 32 + quad * 8);
        short8 bl = *(const short8*)(bl16 + brow + c * 32 + quad * 8);
        acc = __builtin_amdgcn_mfma_f32_16x16x32_bf16(ah, bl, acc, 0, 0, 0);
        acc = __builtin_amdgcn_mfma_f32_16x16x32_bf16(al, bh, acc, 0, 0, 0);
        acc = __builtin_amdgcn_mfma_f32_16x16x32_bf16(ah, bh, acc, 0, 0, 0);
    }
    int c = n0 + m;                   // output c-row
    #pragma unroll
    for (int r = 0; r < 4; ++r) {
        int bkl = lbase + quad * 4 + r;
        float v = acc[r];
        if (c < 6)       dtr[(size_t)bkl * 6 + c] = v;
        else if (c < 22) Bm[(size_t)bkl * 16 + (c - 6)] = v;
        else if (c < 38) Cm[(size_t)bkl * 16 + (c - 22)] = v;
    }
}

// Pass 1: local scan (h_in=0). delta/exp hoisted out of the serial chain.
__global__ __launch_bounds__(192) void k_scan1y(
        const float* __restrict__ xg, const float* __restrict__ dtr,
        const float* __restrict__ Bm, const float* __restrict__ Cm,
        const float* __restrict__ A_logs, const float* __restrict__ dtw,
        const float* __restrict__ dtb, const float* __restrict__ Ds,
        float* __restrict__ Sbuf, unsigned short* __restrict__ Qb,
        float* __restrict__ yout) {
    __shared__ float sU[CHUNK * USTRIDE];
    __shared__ float sB[CHUNK * 16];
    __shared__ float sC[CHUNK * 16];
    int bk = blockIdx.x >> 6;
    int ch = blockIdx.x & 63;
    int k = bk & 3;
    int d = threadIdx.x;
    int lbase = bk * 1024 + ch * CHUNK;
    const float4* usrc = (const float4*)(xg + (size_t)lbase * 192);
    for (int i = d; i < CHUNK * 48; i += 192) {
        int l = i / 48, c4 = i - l * 48;
        *(float4*)&sU[l * USTRIDE + c4 * 4] = usrc[i];
    }
    for (int i = d; i < CHUNK * 16; i += 192) {
        sB[i] = Bm[(size_t)lbase * 16 + i];
        sC[i] = Cm[(size_t)lbase * 16 + i];
    }
    float A[16];
    #pragma unroll
    for (int n = 0; n < 16; ++n) A[n] = -__expf(A_logs[(k * 192 + d) * 16 + n]);
    float A0 = A[0];
    bool geo = true;                 // A[n] == (n+1)*A[0] (geometric ladder)?
    #pragma unroll
    for (int n = 1; n < 16; ++n)
        geo = geo && (fabsf(A[n] - (float)(n + 1) * A0) <= 1e-4f * fabsf(A[n]));
    float wp[6];
    #pragma unroll
    for (int q = 0; q < 6; ++q) wp[q] = dtw[(k * 192 + d) * 6 + q];
    float bias = dtb[k * 192 + d];
    float Dp = Ds[k * 192 + d];
    // ---- delta precompute (independent; overlaps LDS staging latency) ----
    float dlt[CHUNK];
    #pragma unroll 4
    for (int l = 0; l < CHUNK; ++l) {
        const float* r = dtr + (size_t)(lbase + l) * 6;   // wave-uniform
        float a = bias;
        #pragma unroll
        for (int q = 0; q < 6; ++q) a = fmaf(wp[q], r[q], a);
        dlt[l] = softplus_f(a);
    }
    float S = 0.0f;
    #pragma unroll
    for (int l = 0; l < CHUNK; ++l) S += dlt[l];
    __syncthreads();
    float h[16];
    #pragma unroll
    for (int n = 0; n < 16; ++n) h[n] = 0.0f;
    if (geo) {
        float e1v[CHUNK];
        #pragma unroll 4
        for (int l = 0; l < CHUNK; ++l) e1v[l] = __expf(dlt[l] * A0);
        #pragma unroll 2
        for (int l = 0; l < CHUNK; ++l) {
            float u = sU[l * USTRIDE + d];
            float du = dlt[l] * u;
            float e1 = e1v[l];
            float e = e1;
            float y = 0.0f;
            #pragma unroll
            for (int n = 0; n < 16; ++n) {
                h[n] = fmaf(e, h[n], du * sB[l * 16 + n]);
                y = fmaf(h[n], sC[l * 16 + n], y);
                e *= e1;
            }
            yout[(size_t)(lbase + l) * 192 + d] = fmaf(u, Dp, y);
        }
    } else {
        for (int l = 0; l < CHUNK; ++l) {
            float u = sU[l * USTRIDE + d];
            float du = dlt[l] * u;
            float y = 0.0f;
            #pragma unroll
            for (int n = 0; n < 16; ++n) {
                float e = __expf(dlt[l] * A[n]);
                h[n] = fmaf(e, h[n], du * sB[l * 16 + n]);
                y = fmaf(h[n], sC[l * 16 + n], y);
            }
            yout[(size_t)(lbase + l) * 192 + d] = fmaf(u, Dp, y);
        }
    }
    Sbuf[(size_t)ch * SSTRIDE + bk * 192 + d] = S;
    size_t base = (size_t)ch * NSTATES + bk * (192 * 16);
    #pragma unroll
    for (int n = 0; n < 16; ++n)
        Qb[base + n * 192 + d] = f2bf(h[n]);
}

// Pass 2: prefix over chunks; P = exp(A*S). 8x-batched independent loads.
__global__ __launch_bounds__(256) void k_scan2(
        const float* __restrict__ Sbuf, const float* __restrict__ A_logs,
        const unsigned short* __restrict__ Qb, float* __restrict__ Hst) {
    int s = blockIdx.x * 256 + threadIdx.x;   // 0..NSTATES-1
    int bk = s / 3072;                         // 3072 = 16*192
    int rem = s - bk * 3072;
    int n = rem / 192;
    int d = rem - n * 192;
    int k = bk & 3;
    float A = -__expf(A_logs[(k * 192 + d) * 16 + n]);
    int sb = bk * 192 + d;
    float h = 0.0f;
    for (int c0 = 0; c0 < NCH; c0 += 8) {
        float Sv[8], qv[8], pv[8];
        #pragma unroll
        for (int j = 0; j < 8; ++j) {
            Sv[j] = Sbuf[(size_t)(c0 + j) * SSTRIDE + sb];
            qv[j] = bf2f(Qb[(size_t)(c0 + j) * NSTATES + s]);
        }
        #pragma unroll
        for (int j = 0; j < 8; ++j) pv[j] = __expf(A * Sv[j]);
        #pragma unroll
        for (int j = 0; j < 8; ++j) {
            Hst[(size_t)(c0 + j) * NSTATES + s] = h;
            h = fmaf(pv[j], h, qv[j]);
        }
    }
}

// Pass 3: chain-free correction; all decays precomputed (no transcendentals
// in the work loop). yout[l,d] += sum_n C[l,n]*exp(A[n]*S_l)*h0[n].
__global__ __launch_bounds__(192) void k_scan3c(
        const float* __restrict__ dtr, const float* __restrict__ Cm,
        const float* __restrict__ A_logs, const float* __restrict__ dtw,
        const float* __restrict__ dtb, const float* __restrict__ Hst,
        float* __restrict__ yout) {
    __shared__ float sC[CHUNK * 16];
    int bk = blockIdx.x >> 6;
    int ch = blockIdx.x & 63;
    if (ch == 0) return;              // h0 == 0, no correction
    int k = bk & 3;
    int d = threadIdx.x;
    int lbase = bk * 1024 + ch * CHUNK;
    for (int i = d; i < CHUNK * 16; i += 192)
        sC[i] = Cm[(size_t)lbase * 16 + i];
    float A[16];
    #pragma unroll
    for (int n = 0; n < 16; ++n) A[n] = -__expf(A_logs[(k * 192 + d) * 16 + n]);
    float A0 = A[0];
    bool geo = true;
    #pragma unroll
    for (int n = 1; n < 16; ++n)
        geo = geo && (fabsf(A[n] - (float)(n + 1) * A0) <= 1e-4f * fabsf(A[n]));
    float wp[6];
    #pragma unroll
    for (int q = 0; q < 6; ++q) wp[q] = dtw[(k * 192 + d) * 6 + q];
    float bias = dtb[k * 192 + d];
    float h0[16];
    size_t base = (size_t)ch * NSTATES + bk * (192 * 16);
    #pragma unroll
    for (int n = 0; n < 16; ++n) h0[n] = Hst[base + n * 192 + d];
    // ---- precompute delta, prefix S_l, decay bases ----
    float Sarr[CHUNK];
    {
        float S = 0.0f;
        #pragma unroll 4
        for (int l = 0; l < CHUNK; ++l) {
            const float* r = dtr + (size_t)(lbase + l) * 6;   // wave-uniform
            float a = bias;
            #pragma unroll
            for (int q = 0; q < 6; ++q) a = fmaf(wp[q], r[q], a);
            S += softplus_f(a);
            Sarr[l] = S;
        }
    }
    __syncthreads();
    if (geo) {
        float e1l[CHUNK];
        #pragma unroll 4
        for (int l = 0; l < CHUNK; ++l) e1l[l] = __expf(A0 * Sarr[l]);
        #pragma unroll 2
        for (int l = 0; l < CHUNK; ++l) {
            float y = yout[(size_t)(lbase + l) * 192 + d];
            float e1 = e1l[l];
            float e = e1;
            float corr = 0.0f;
            #pragma unroll
            for (int n = 0; n < 16; ++n) {
                corr = fmaf(h0[n] * e, sC[l * 16 + n], corr);
                e *= e1;
            }
            yout[(size_t)(lbase + l) * 192 + d] = y + corr;
        }
    } else {
        for (int l = 0; l < CHUNK; ++l) {
            float y = yout[(size_t)(lbase + l) * 192 + d];
            float corr = 0.0f;
            #pragma unroll
            for (int n = 0; n < 16; ++n) {
                float e = __expf(A[n] * Sarr[l]);
                corr = fmaf(h0[n] * e, sC[l * 16 + n], corr);
            }
            yout[(size_t)(lbase + l) * 192 + d] = y + corr;
        }
    }
}

// merge + LayerNorm + gate (bf16 z) -> g (bf16, LDS) -> MFMA out GEMM.
__global__ __launch_bounds__(256) void k_lnout(
        const float* __restrict__ yout, const unsigned short* __restrict__ zb,
        const float* __restrict__ lng, const float* __restrict__ lnb,
        const unsigned short* __restrict__ Wo_bf, float* __restrict__ out) {
    __shared__ __align__(16) short sgb[32 * GSTRIDE];
    int p0 = blockIdx.x * 32;
    int t = threadIdx.x;
    int p = t >> 3;                    // pixel 0..31
    int sub = t & 7;                   // 8 threads per pixel, 24 channels each
    int gp = p0 + p;
    int b = gp >> 12;
    int hw = gp & 4095;
    int h = hw >> 6, w = hw & 63;
    int kq = (h & 1) ? ((w & 1) ? 3 : 1) : ((w & 1) ? 2 : 0);
    int l = (kq & 1) ? ((w >> 1) * 32 + (h >> 1))
                     : ((h >> 1) * 32 + (w >> 1));
    const float* yrow = yout + ((size_t)(b * 4 + kq) * 1024 + l) * 192 + sub * 24;
    float4 yv[6];
    float s = 0.0f, s2 = 0.0f;
    #pragma unroll
    for (int j = 0; j < 6; ++j) {
        float4 v = *(const float4*)(yrow + j * 4);
        yv[j] = v;
        s += v.x + v.y + v.z + v.w;
        s2 += v.x * v.x + v.y * v.y + v.z * v.z + v.w * v.w;
    }
    #pragma unroll
    for (int off = 1; off < 8; off <<= 1) {
        s  += __shfl_xor(s, off, 8);
        s2 += __shfl_xor(s2, off, 8);
    }
    float mu = s * (1.0f / 192.0f);
    float var = s2 * (1.0f / 192.0f) - mu * mu;
    float rstd = rsqrtf(var + 1e-5f);
    const unsigned short* zrow = zb + (size_t)gp * 192 + sub * 24;
    short* grow = sgb + p * GSTRIDE + sub * 24;
    #pragma unroll
    for (int j = 0; j < 6; ++j) {
        ushort4v zv4 = *(const ushort4v*)(zrow + j * 4);
        float4 gv = *(const float4*)(lng + sub * 24 + j * 4);
        float4 bv = *(const float4*)(lnb + sub * 24 + j * 4);
        short4v sv;
        sv.x = (short)f2bf(((yv[j].x - mu) * rstd * gv.x + bv.x) * bf2f(zv4.x));
        sv.y = (short)f2bf(((yv[j].y - mu) * rstd * gv.y + bv.y) * bf2f(zv4.y));
        sv.z = (short)f2bf(((yv[j].z - mu) * rstd * gv.z + bv.z) * bf2f(zv4.z));
        sv.w = (short)f2bf(((yv[j].w - mu) * rstd * gv.w + bv.w) * bf2f(zv4.w));
        *(short4v*)(grow + j * 4) = sv;
    }
    __syncthreads();
    int wv = t >> 6;
    int lane = t & 63;
    int m = lane & 15, quad = lane >> 4;
    int mt = wv >> 1;
    int nb = (wv & 1) * 3;
    const short* wob = (const short*)Wo_bf;
    short8 a[6];
    #pragma unroll
    for (int kk = 0; kk < 6; ++kk)
        a[kk] = *(const short8*)(sgb + (mt * 16 + m) * GSTRIDE + kk * 32 + quad * 8);
    #pragma unroll
    for (int i = 0; i < 3; ++i) {
        int n0 = (nb + i) * 16;
        f32x4 acc = {0.f, 0.f, 0.f, 0.f};
        #pragma unroll
        for (int kk = 0; kk < 6; ++kk) {
            short8 bfr = *(const short8*)(wob + (size_t)(n0 + m) * 192 + kk * 32 + quad * 8);
            acc = __builtin_amdgcn_mfma_f32_16x16x32_bf16(a[kk], bfr, acc, 0, 0, 0);
        }
        #pragma unroll
        for (int r = 0; r < 4; ++r) {
            int pp = p0 + mt * 16 + quad * 4 + r;
            out[(size_t)pp * 96 + n0 + m] = acc[r];
        }
    }
}

extern "C" void kernel_launch(void* const* d_in, const int* in_sizes, int n_in,
                              void* d_out, int out_size, void* d_ws, size_t ws_size,
                              hipStream_t stream) {
    const float* x    = (const float*)d_in[0];
    const float* W_in = (const float*)d_in[1];
    const float* cw   = (const float*)d_in[2];
    const float* cb   = (const float*)d_in[3];
    const float* xpw  = (const float*)d_in[4];
    const float* dtw  = (const float*)d_in[5];
    const float* dtb  = (const float*)d_in[6];
    const float* Alog = (const float*)d_in[7];
    const float* Ds   = (const float*)d_in[8];
    const float* lng  = (const float*)d_in[9];
    const float* lnb  = (const float*)d_in[10];
    const float* Wout = (const float*)d_in[11];
    float* out = (float*)d_out;

    float* ws = (float*)d_ws;
    size_t off = 0;
    unsigned short* Wi_hi = (unsigned short*)(ws + off); off += 384 * 96 / 2;
    unsigned short* Wi_lo = (unsigned short*)(ws + off); off += 384 * 96 / 2;
    unsigned short* Xp_hi = (unsigned short*)(ws + off); off += 4 * 48 * 192 / 2;
    unsigned short* Xp_lo = (unsigned short*)(ws + off); off += 4 * 48 * 192 / 2;
    unsigned short* Wo_bf = (unsigned short*)(ws + off); off += 96 * DINNER / 2;
    float* xin   = ws + off; off += (size_t)NPIX * 192;
    unsigned short* zb = (unsigned short*)(ws + off); off += (size_t)NPIX * 192 / 2;
    float* xg    = ws + off; off += (size_t)NPIX * 192;
    float* dtrb  = ws + off; off += (size_t)NBK * LP * 6;
    float* Bm    = ws + off; off += (size_t)NBK * LP * 16;
    float* Cm    = ws + off; off += (size_t)NBK * LP * 16;
    float* Sbuf  = ws + off; off += (size_t)NCH * SSTRIDE;
    unsigned short* Qb = (unsigned short*)(ws + off); off += (size_t)NCH * NSTATES / 2;
    float* Hst   = ws + off; off += (size_t)NCH * NSTATES;
    float* yout  = ws + off; off += (size_t)NBK * LP * 192;

    hipLaunchKernelGGL(k_castW, dim3(144), dim3(256), 0, stream,
                       W_in, xpw, Wout, Wi_hi, Wi_lo, Xp_hi, Xp_lo, Wo_bf);
    hipLaunchKernelGGL(k_inproj3, dim3(NPIX / 16), dim3(256), 0, stream,
                       x, Wi_hi, Wi_lo, xin, zb);
    hipLaunchKernelGGL(k_conv8, dim3(NPIX / 8), dim3(192), 0, stream,
                       xin, cw, cb, xg);
    hipLaunchKernelGGL(k_xdbl, dim3(NBK * 64), dim3(192), 0, stream,
                       xg, Xp_hi, Xp_lo, dtrb, Bm, Cm);
    hipLaunchKernelGGL(k_scan1y, dim3(NBK * NCH), dim3(192), 0, stream,
                       xg, dtrb, Bm, Cm, Alog, dtw, dtb, Ds, Sbuf, Qb, yout);
    hipLaunchKernelGGL(k_scan2, dim3(NSTATES / 256), dim3(256), 0, stream,
                       Sbuf, Alog, Qb, Hst);
    hipLaunchKernelGGL(k_scan3c, dim3(NBK * NCH), dim3(192), 0, stream,
                       dtrb, Cm, Alog, dtw, dtb, Hst, yout);
    hipLaunchKernelGGL(k_lnout, dim3(NPIX / 32), dim3(256), 0, stream,
                       yout, zb, lng, lnb, Wo_bf, out);
}

// Round 17
// 157.798 us; speedup vs baseline: 1.1064x; 1.0013x over previous
//
#include <hip/hip_runtime.h>
#include <math.h>

// SS2D (VMamba v2) forward — MI355X gfx950.
// fp32 scan core; MFMA bf16x3-split in-proj AND x_dbl GEMM; MFMA bf16 out-proj.
// bf16 intermediates on direct error paths: z, Q, yout, Hst.
//
// Pipeline (8 dispatches):
//  k_castW   : W_in -> (hi,lo); xpw -> (hi,lo, 48-row padded); W_out -> bf16
//  k_inproj3 : xz = x @ W_in^T via bf16x3 MFMA; A-split staged ONCE in LDS
//  k_conv8   : depthwise 3x3 (window preloaded to regs) + bias + silu -> xg
//  k_xdbl    : x_dbl via bf16x3 MFMA (u-tile split in LDS) -> dtr/Bm/Cm
//  k_scan1y  : local scan -> y_local (bf16) to yout, Q (bf16), S
//  k_scan2   : prefix over 64 chunks (8x-batched); Hst (bf16)
//  k_scan3c  : chain-free correction on bf16 yout
//  k_lnout   : merge + LayerNorm + gate(bf16 z) -> bf16 LDS -> MFMA out GEMM

#define DINNER 192
#define NSTATE 16
#define KDIR 4
#define BATCH 4
#define NPIX (BATCH * 64 * 64)          // 16384
#define LP 1024
#define NCH 64                          // scan chunks
#define CHUNK 16                        // LP / NCH
#define NBK (BATCH * KDIR)              // 16
#define NSTATES (NBK * DINNER * NSTATE) // 49152
#define SSTRIDE (NBK * DINNER)          // 3072 floats of S per chunk
#define USTRIDE 196                     // scan sU row stride (floats)
#define GSTRIDE 200                     // lnout bf16 g LDS stride (shorts)
#define ASTRIDE 104                     // inproj LDS A stride (shorts, 96 padded)
#define XSTRIDE 200                     // xdbl LDS A stride (shorts, 192 padded)

typedef __attribute__((ext_vector_type(8))) short short8;
typedef __attribute__((ext_vector_type(4))) short short4v;
typedef __attribute__((ext_vector_type(4))) unsigned short ushort4v;
typedef __attribute__((ext_vector_type(8))) unsigned short ushort8v;
typedef __attribute__((ext_vector_type(4))) float f32x4;

__device__ __forceinline__ float silu_f(float x) {
    return x / (1.0f + __expf(-x));
}
__device__ __forceinline__ float softplus_f(float a) {
    return (a > 20.0f) ? a : __logf(1.0f + __expf(a));
}
__device__ __forceinline__ unsigned short f2bf(float f) {
    unsigned u = __float_as_uint(f);
    unsigned r = (u + 0x7FFFu + ((u >> 16) & 1u)) >> 16;
    return (unsigned short)r;
}
__device__ __forceinline__ float bf2f(unsigned short h) {
    return __uint_as_float(((unsigned)h) << 16);
}

// Weights: W_in hi/lo split; xpw hi/lo split into 48-row padded layout
// (rows 38..47 zero); W_out bf16 cast.
__global__ __launch_bounds__(256) void k_castW(
        const float* __restrict__ W_in, const float* __restrict__ xpw,
        const float* __restrict__ W_out,
        unsigned short* __restrict__ Wi_hi, unsigned short* __restrict__ Wi_lo,
        unsigned short* __restrict__ Xp_hi, unsigned short* __restrict__ Xp_lo,
        unsigned short* __restrict__ Wo_bf) {
    int i = blockIdx.x * 256 + threadIdx.x;
    if (i < 384 * 96) {
        float v = W_in[i];
        unsigned short h = f2bf(v);
        Wi_hi[i] = h;
        Wi_lo[i] = f2bf(v - bf2f(h));
    }
    if (i < 4 * 48 * 192) {           // padded xpw split
        int kk = i / (48 * 192);
        int rem = i - kk * (48 * 192);
        int c = rem / 192;
        int j = rem - c * 192;
        float v = (c < 38) ? xpw[((size_t)kk * 38 + c) * 192 + j] : 0.0f;
        unsigned short h = f2bf(v);
        Xp_hi[i] = h;
        Xp_lo[i] = f2bf(v - bf2f(h));
    }
    if (i < 96 * DINNER) Wo_bf[i] = f2bf(W_out[i]);
}

// MFMA in-proj (bf16x3 split); x split staged ONCE in LDS (shared by 4 waves).
__global__ __launch_bounds__(256) void k_inproj3(
        const float* __restrict__ x,
        const unsigned short* __restrict__ Wi_hi,
        const unsigned short* __restrict__ Wi_lo,
        float* __restrict__ xin, unsigned short* __restrict__ zb) {
    __shared__ __align__(16) short sAh[16 * ASTRIDE];
    __shared__ __align__(16) short sAl[16 * ASTRIDE];
    int p0 = blockIdx.x * 16;
    int t = threadIdx.x;
    const float4* xs = (const float4*)(x + (size_t)p0 * 96);
    for (int i = t; i < 384; i += 256) {     // 16*96 floats = 384 float4
        float4 v = xs[i];
        int f = i * 4;
        int row = f / 96, col = f - row * 96;
        short4v hi, lo;
        unsigned short hb;
        hb = f2bf(v.x); hi.x = (short)hb; lo.x = (short)f2bf(v.x - bf2f(hb));
        hb = f2bf(v.y); hi.y = (short)hb; lo.y = (short)f2bf(v.y - bf2f(hb));
        hb = f2bf(v.z); hi.z = (short)hb; lo.z = (short)f2bf(v.z - bf2f(hb));
        hb = f2bf(v.w); hi.w = (short)hb; lo.w = (short)f2bf(v.w - bf2f(hb));
        *(short4v*)&sAh[row * ASTRIDE + col] = hi;
        *(short4v*)&sAl[row * ASTRIDE + col] = lo;
    }
    __syncthreads();
    int w = t >> 6;
    int lane = t & 63;
    int m = lane & 15, quad = lane >> 4;
    const short* wh = (const short*)Wi_hi;
    const short* wl = (const short*)Wi_lo;
    short8 ah[3], al[3];
    #pragma unroll
    for (int c = 0; c < 3; ++c) {
        ah[c] = *(const short8*)&sAh[m * ASTRIDE + c * 32 + quad * 8];
        al[c] = *(const short8*)&sAl[m * ASTRIDE + c * 32 + quad * 8];
    }
    #pragma unroll
    for (int i = 0; i < 6; ++i) {
        int e0 = (w * 6 + i) * 16;
        f32x4 acc = {0.f, 0.f, 0.f, 0.f};
        #pragma unroll
        for (int c = 0; c < 3; ++c) {
            size_t o = (size_t)(e0 + m) * 96 + c * 32 + quad * 8;
            short8 bh = *(const short8*)(wh + o);
            short8 bl = *(const short8*)(wl + o);
            acc = __builtin_amdgcn_mfma_f32_16x16x32_bf16(ah[c], bl, acc, 0, 0, 0);
            acc = __builtin_amdgcn_mfma_f32_16x16x32_bf16(al[c], bh, acc, 0, 0, 0);
            acc = __builtin_amdgcn_mfma_f32_16x16x32_bf16(ah[c], bh, acc, 0, 0, 0);
        }
        int e = e0 + m;
        #pragma unroll
        for (int r = 0; r < 4; ++r) {
            int p = p0 + quad * 4 + r;
            if (e < 192) xin[(size_t)p * 192 + e] = acc[r];
            else         zb[(size_t)p * 192 + (e - 192)] = f2bf(silu_f(acc[r]));
        }
    }
}

// depthwise 3x3, 8 pixels/block; full 3x10 window preloaded into registers.
__global__ __launch_bounds__(192) void k_conv8(
        const float* __restrict__ xin, const float* __restrict__ cw,
        const float* __restrict__ cb, float* __restrict__ xg) {
    int blk = blockIdx.x;             // 2048 = 4 b * 64 h * 8 wchunks
    int b = blk >> 9;
    int rem = blk & 511;
    int h = rem >> 3;
    int w0 = (rem & 7) * 8;
    int d = threadIdx.x;
    float wr[3][3];
    #pragma unroll
    for (int i = 0; i < 3; ++i)
        #pragma unroll
        for (int j = 0; j < 3; ++j) wr[i][j] = cw[d * 9 + i * 3 + j];
    float bias = cb[d];
    float r0[10], r1[10], r2[10];
    #pragma unroll
    for (int jj = 0; jj < 10; ++jj) {
        int ww = w0 + jj - 1;
        bool inw = (unsigned)ww < 64u;        // block-uniform
        const float* base = xin + ((size_t)b * 4096 + h * 64 + (inw ? ww : 0)) * 192 + d;
        r0[jj] = (inw && h > 0)  ? base[-64 * 192] : 0.0f;
        r1[jj] = inw             ? base[0]         : 0.0f;
        r2[jj] = (inw && h < 63) ? base[64 * 192]  : 0.0f;
    }
    float acc[8];
    #pragma unroll
    for (int o = 0; o < 8; ++o) {
        float a = bias;
        #pragma unroll
        for (int j = 0; j < 3; ++j) {
            a = fmaf(r0[o + j], wr[0][j], a);
            a = fmaf(r1[o + j], wr[1][j], a);
            a = fmaf(r2[o + j], wr[2][j], a);
        }
        acc[o] = a;
    }
    #pragma unroll
    for (int o = 0; o < 8; ++o) {
        int w = w0 + o;
        int kq = (h & 1) ? ((w & 1) ? 3 : 1) : ((w & 1) ? 2 : 0);
        int l = (kq & 1) ? ((w >> 1) * 32 + (h >> 1))
                         : ((h >> 1) * 32 + (w >> 1));
        xg[((size_t)(b * 4 + kq) * 1024 + l) * 192 + d] = silu_f(acc[o]);
    }
}

// x_dbl via bf16x3 MFMA: per (bk, 16-l tile). 3 waves = 3 N-tiles (48 c-rows,
// 38 valid). A = u-tile split in LDS; B = padded Xp hi/lo (row-major).
__global__ __launch_bounds__(192) void k_xdbl(
        const float* __restrict__ xg,
        const unsigned short* __restrict__ Xp_hi,
        const unsigned short* __restrict__ Xp_lo,
        float* __restrict__ dtr, float* __restrict__ Bm, float* __restrict__ Cm) {
    __shared__ __align__(16) short sAh[16 * XSTRIDE];
    __shared__ __align__(16) short sAl[16 * XSTRIDE];
    int bk = blockIdx.x >> 6;
    int tile = blockIdx.x & 63;
    int k = bk & 3;
    int t = threadIdx.x;
    int lbase = bk * 1024 + tile * 16;
    const float4* us = (const float4*)(xg + (size_t)lbase * 192);
    for (int i = t; i < 768; i += 192) {     // 16*192 floats = 768 float4
        float4 v = us[i];
        int f = i * 4;
        int row = f / 192, col = f - row * 192;
        short4v hi, lo;
        unsigned short hb;
        hb = f2bf(v.x); hi.x = (short)hb; lo.x = (short)f2bf(v.x - bf2f(hb));
        hb = f2bf(v.y); hi.y = (short)hb; lo.y = (short)f2bf(v.y - bf2f(hb));
        hb = f2bf(v.z); hi.z = (short)hb; lo.z = (short)f2bf(v.z - bf2f(hb));
        hb = f2bf(v.w); hi.w = (short)hb; lo.w = (short)f2bf(v.w - bf2f(hb));
        *(short4v*)&sAh[row * XSTRIDE + col] = hi;
        *(short4v*)&sAl[row * XSTRIDE + col] = lo;
    }
    __syncthreads();
    int wv = t >> 6;                  // N-tile 0..2
    int lane = t & 63;
    int m = lane & 15, quad = lane >> 4;
    const short* bh16 = (const short*)Xp_hi;
    const short* bl16 = (const short*)Xp_lo;
    int n0 = wv * 16;
    size_t brow = ((size_t)k * 48 + n0 + m) * 192;
    f32x4 acc = {0.f, 0.f, 0.f, 0.f};
    #pragma unroll
    for (int c = 0; c < 6; ++c) {
        short8 ah = *(const short8*)&sAh[m * XSTRIDE + c * 32 + quad * 8];
        short8 al = *(const short8*)&sAl[m * XSTRIDE + c * 32 + quad * 8];
        short8 bh = *(const short8*)(bh16 + brow + c * 32 + quad * 8);
        short8 bl = *(const short8*)(bl16 + brow + c * 32 + quad * 8);
        acc = __builtin_amdgcn_mfma_f32_16x16x32_bf16(ah, bl, acc, 0, 0, 0);
        acc = __builtin_amdgcn_mfma_f32_16x16x32_bf16(al, bh, acc, 0, 0, 0);
        acc = __builtin_amdgcn_mfma_f32_16x16x32_bf16(ah, bh, acc, 0, 0, 0);
    }
    int c = n0 + m;                   // output c-row
    #pragma unroll
    for (int r = 0; r < 4; ++r) {
        int bkl = lbase + quad * 4 + r;
        float v = acc[r];
        if (c < 6)       dtr[(size_t)bkl * 6 + c] = v;
        else if (c < 22) Bm[(size_t)bkl * 16 + (c - 6)] = v;
        else if (c < 38) Cm[(size_t)bkl * 16 + (c - 22)] = v;
    }
}

// Pass 1: local scan (h_in=0). Emits y_local (bf16) to yout, Q (bf16), S.
__global__ __launch_bounds__(192) void k_scan1y(
        const float* __restrict__ xg, const float* __restrict__ dtr,
        const float* __restrict__ Bm, const float* __restrict__ Cm,
        const float* __restrict__ A_logs, const float* __restrict__ dtw,
        const float* __restrict__ dtb, const float* __restrict__ Ds,
        float* __restrict__ Sbuf, unsigned short* __restrict__ Qb,
        unsigned short* __restrict__ yout) {
    __shared__ float sU[CHUNK * USTRIDE];
    __shared__ float sB[CHUNK * 16];
    __shared__ float sC[CHUNK * 16];
    int bk = blockIdx.x >> 6;
    int ch = blockIdx.x & 63;
    int k = bk & 3;
    int d = threadIdx.x;
    int lbase = bk * 1024 + ch * CHUNK;
    const float4* usrc = (const float4*)(xg + (size_t)lbase * 192);
    for (int i = d; i < CHUNK * 48; i += 192) {
        int l = i / 48, c4 = i - l * 48;
        *(float4*)&sU[l * USTRIDE + c4 * 4] = usrc[i];
    }
    for (int i = d; i < CHUNK * 16; i += 192) {
        sB[i] = Bm[(size_t)lbase * 16 + i];
        sC[i] = Cm[(size_t)lbase * 16 + i];
    }
    float A[16];
    #pragma unroll
    for (int n = 0; n < 16; ++n) A[n] = -__expf(A_logs[(k * 192 + d) * 16 + n]);
    float A0 = A[0];
    bool geo = true;                 // A[n] == (n+1)*A[0] (geometric ladder)?
    #pragma unroll
    for (int n = 1; n < 16; ++n)
        geo = geo && (fabsf(A[n] - (float)(n + 1) * A0) <= 1e-4f * fabsf(A[n]));
    float wp[6];
    #pragma unroll
    for (int q = 0; q < 6; ++q) wp[q] = dtw[(k * 192 + d) * 6 + q];
    float bias = dtb[k * 192 + d];
    float Dp = Ds[k * 192 + d];
    float dlt[CHUNK];
    #pragma unroll 4
    for (int l = 0; l < CHUNK; ++l) {
        const float* r = dtr + (size_t)(lbase + l) * 6;   // wave-uniform
        float a = bias;
        #pragma unroll
        for (int q = 0; q < 6; ++q) a = fmaf(wp[q], r[q], a);
        dlt[l] = softplus_f(a);
    }
    float S = 0.0f;
    #pragma unroll
    for (int l = 0; l < CHUNK; ++l) S += dlt[l];
    __syncthreads();
    float h[16];
    #pragma unroll
    for (int n = 0; n < 16; ++n) h[n] = 0.0f;
    if (geo) {
        float e1v[CHUNK];
        #pragma unroll 4
        for (int l = 0; l < CHUNK; ++l) e1v[l] = __expf(dlt[l] * A0);
        #pragma unroll 2
        for (int l = 0; l < CHUNK; ++l) {
            float u = sU[l * USTRIDE + d];
            float du = dlt[l] * u;
            float e1 = e1v[l];
            float e = e1;
            float y = 0.0f;
            #pragma unroll
            for (int n = 0; n < 16; ++n) {
                h[n] = fmaf(e, h[n], du * sB[l * 16 + n]);
                y = fmaf(h[n], sC[l * 16 + n], y);
                e *= e1;
            }
            yout[(size_t)(lbase + l) * 192 + d] = f2bf(fmaf(u, Dp, y));
        }
    } else {
        for (int l = 0; l < CHUNK; ++l) {
            float u = sU[l * USTRIDE + d];
            float du = dlt[l] * u;
            float y = 0.0f;
            #pragma unroll
            for (int n = 0; n < 16; ++n) {
                float e = __expf(dlt[l] * A[n]);
                h[n] = fmaf(e, h[n], du * sB[l * 16 + n]);
                y = fmaf(h[n], sC[l * 16 + n], y);
            }
            yout[(size_t)(lbase + l) * 192 + d] = f2bf(fmaf(u, Dp, y));
        }
    }
    Sbuf[(size_t)ch * SSTRIDE + bk * 192 + d] = S;
    size_t base = (size_t)ch * NSTATES + bk * (192 * 16);
    #pragma unroll
    for (int n = 0; n < 16; ++n)
        Qb[base + n * 192 + d] = f2bf(h[n]);
}

// Pass 2: prefix over chunks; P = exp(A*S). 8x-batched. Hst bf16.
__global__ __launch_bounds__(256) void k_scan2(
        const float* __restrict__ Sbuf, const float* __restrict__ A_logs,
        const unsigned short* __restrict__ Qb, unsigned short* __restrict__ Hst) {
    int s = blockIdx.x * 256 + threadIdx.x;   // 0..NSTATES-1
    int bk = s / 3072;                         // 3072 = 16*192
    int rem = s - bk * 3072;
    int n = rem / 192;
    int d = rem - n * 192;
    int k = bk & 3;
    float A = -__expf(A_logs[(k * 192 + d) * 16 + n]);
    int sb = bk * 192 + d;
    float h = 0.0f;
    for (int c0 = 0; c0 < NCH; c0 += 8) {
        float Sv[8], qv[8], pv[8];
        #pragma unroll
        for (int j = 0; j < 8; ++j) {
            Sv[j] = Sbuf[(size_t)(c0 + j) * SSTRIDE + sb];
            qv[j] = bf2f(Qb[(size_t)(c0 + j) * NSTATES + s]);
        }
        #pragma unroll
        for (int j = 0; j < 8; ++j) pv[j] = __expf(A * Sv[j]);
        #pragma unroll
        for (int j = 0; j < 8; ++j) {
            Hst[(size_t)(c0 + j) * NSTATES + s] = f2bf(h);
            h = fmaf(pv[j], h, qv[j]);
        }
    }
}

// Pass 3: chain-free correction on bf16 yout; decays precomputed.
__global__ __launch_bounds__(192) void k_scan3c(
        const float* __restrict__ dtr, const float* __restrict__ Cm,
        const float* __restrict__ A_logs, const float* __restrict__ dtw,
        const float* __restrict__ dtb, const unsigned short* __restrict__ Hst,
        unsigned short* __restrict__ yout) {
    __shared__ float sC[CHUNK * 16];
    int bk = blockIdx.x >> 6;
    int ch = blockIdx.x & 63;
    if (ch == 0) return;              // h0 == 0, no correction
    int k = bk & 3;
    int d = threadIdx.x;
    int lbase = bk * 1024 + ch * CHUNK;
    for (int i = d; i < CHUNK * 16; i += 192)
        sC[i] = Cm[(size_t)lbase * 16 + i];
    float A[16];
    #pragma unroll
    for (int n = 0; n < 16; ++n) A[n] = -__expf(A_logs[(k * 192 + d) * 16 + n]);
    float A0 = A[0];
    bool geo = true;
    #pragma unroll
    for (int n = 1; n < 16; ++n)
        geo = geo && (fabsf(A[n] - (float)(n + 1) * A0) <= 1e-4f * fabsf(A[n]));
    float wp[6];
    #pragma unroll
    for (int q = 0; q < 6; ++q) wp[q] = dtw[(k * 192 + d) * 6 + q];
    float bias = dtb[k * 192 + d];
    float h0[16];
    size_t base = (size_t)ch * NSTATES + bk * (192 * 16);
    #pragma unroll
    for (int n = 0; n < 16; ++n) h0[n] = bf2f(Hst[base + n * 192 + d]);
    float Sarr[CHUNK];
    {
        float S = 0.0f;
        #pragma unroll 4
        for (int l = 0; l < CHUNK; ++l) {
            const float* r = dtr + (size_t)(lbase + l) * 6;   // wave-uniform
            float a = bias;
            #pragma unroll
            for (int q = 0; q < 6; ++q) a = fmaf(wp[q], r[q], a);
            S += softplus_f(a);
            Sarr[l] = S;
        }
    }
    __syncthreads();
    if (geo) {
        float e1l[CHUNK];
        #pragma unroll 4
        for (int l = 0; l < CHUNK; ++l) e1l[l] = __expf(A0 * Sarr[l]);
        #pragma unroll 2
        for (int l = 0; l < CHUNK; ++l) {
            float y = bf2f(yout[(size_t)(lbase + l) * 192 + d]);
            float e1 = e1l[l];
            float e = e1;
            float corr = 0.0f;
            #pragma unroll
            for (int n = 0; n < 16; ++n) {
                corr = fmaf(h0[n] * e, sC[l * 16 + n], corr);
                e *= e1;
            }
            yout[(size_t)(lbase + l) * 192 + d] = f2bf(y + corr);
        }
    } else {
        for (int l = 0; l < CHUNK; ++l) {
            float y = bf2f(yout[(size_t)(lbase + l) * 192 + d]);
            float corr = 0.0f;
            #pragma unroll
            for (int n = 0; n < 16; ++n) {
                float e = __expf(A[n] * Sarr[l]);
                corr = fmaf(h0[n] * e, sC[l * 16 + n], corr);
            }
            yout[(size_t)(lbase + l) * 192 + d] = f2bf(y + corr);
        }
    }
}

// merge + LayerNorm + gate (bf16 z) -> g (bf16, LDS) -> MFMA out GEMM.
__global__ __launch_bounds__(256) void k_lnout(
        const unsigned short* __restrict__ yout,
        const unsigned short* __restrict__ zb,
        const float* __restrict__ lng, const float* __restrict__ lnb,
        const unsigned short* __restrict__ Wo_bf, float* __restrict__ out) {
    __shared__ __align__(16) short sgb[32 * GSTRIDE];
    int p0 = blockIdx.x * 32;
    int t = threadIdx.x;
    int p = t >> 3;                    // pixel 0..31
    int sub = t & 7;                   // 8 threads per pixel, 24 channels each
    int gp = p0 + p;
    int b = gp >> 12;
    int hw = gp & 4095;
    int h = hw >> 6, w = hw & 63;
    int kq = (h & 1) ? ((w & 1) ? 3 : 1) : ((w & 1) ? 2 : 0);
    int l = (kq & 1) ? ((w >> 1) * 32 + (h >> 1))
                     : ((h >> 1) * 32 + (w >> 1));
    const unsigned short* yrow =
        yout + ((size_t)(b * 4 + kq) * 1024 + l) * 192 + sub * 24;
    float yv[24];
    float s = 0.0f, s2 = 0.0f;
    #pragma unroll
    for (int j = 0; j < 3; ++j) {
        ushort8v v8 = *(const ushort8v*)(yrow + j * 8);
        #pragma unroll
        for (int e = 0; e < 8; ++e) {
            float v = bf2f(v8[e]);
            yv[j * 8 + e] = v;
            s += v;
            s2 += v * v;
        }
    }
    #pragma unroll
    for (int off = 1; off < 8; off <<= 1) {
        s  += __shfl_xor(s, off, 8);
        s2 += __shfl_xor(s2, off, 8);
    }
    float mu = s * (1.0f / 192.0f);
    float var = s2 * (1.0f / 192.0f) - mu * mu;
    float rstd = rsqrtf(var + 1e-5f);
    const unsigned short* zrow = zb + (size_t)gp * 192 + sub * 24;
    short* grow = sgb + p * GSTRIDE + sub * 24;
    #pragma unroll
    for (int j = 0; j < 6; ++j) {
        ushort4v zv4 = *(const ushort4v*)(zrow + j * 4);
        float4 gv = *(const float4*)(lng + sub * 24 + j * 4);
        float4 bv = *(const float4*)(lnb + sub * 24 + j * 4);
        short4v sv;
        sv.x = (short)f2bf(((yv[j * 4 + 0] - mu) * rstd * gv.x + bv.x) * bf2f(zv4.x));
        sv.y = (short)f2bf(((yv[j * 4 + 1] - mu) * rstd * gv.y + bv.y) * bf2f(zv4.y));
        sv.z = (short)f2bf(((yv[j * 4 + 2] - mu) * rstd * gv.z + bv.z) * bf2f(zv4.z));
        sv.w = (short)f2bf(((yv[j * 4 + 3] - mu) * rstd * gv.w + bv.w) * bf2f(zv4.w));
        *(short4v*)(grow + j * 4) = sv;
    }
    __syncthreads();
    int wv = t >> 6;
    int lane = t & 63;
    int m = lane & 15, quad = lane >> 4;
    int mt = wv >> 1;
    int nb = (wv & 1) * 3;
    const short* wob = (const short*)Wo_bf;
    short8 a[6];
    #pragma unroll
    for (int kk = 0; kk < 6; ++kk)
        a[kk] = *(const short8*)(sgb + (mt * 16 + m) * GSTRIDE + kk * 32 + quad * 8);
    #pragma unroll
    for (int i = 0; i < 3; ++i) {
        int n0 = (nb + i) * 16;
        f32x4 acc = {0.f, 0.f, 0.f, 0.f};
        #pragma unroll
        for (int kk = 0; kk < 6; ++kk) {
            short8 bfr = *(const short8*)(wob + (size_t)(n0 + m) * 192 + kk * 32 + quad * 8);
            acc = __builtin_amdgcn_mfma_f32_16x16x32_bf16(a[kk], bfr, acc, 0, 0, 0);
        }
        #pragma unroll
        for (int r = 0; r < 4; ++r) {
            int pp = p0 + mt * 16 + quad * 4 + r;
            out[(size_t)pp * 96 + n0 + m] = acc[r];
        }
    }
}

extern "C" void kernel_launch(void* const* d_in, const int* in_sizes, int n_in,
                              void* d_out, int out_size, void* d_ws, size_t ws_size,
                              hipStream_t stream) {
    const float* x    = (const float*)d_in[0];
    const float* W_in = (const float*)d_in[1];
    const float* cw   = (const float*)d_in[2];
    const float* cb   = (const float*)d_in[3];
    const float* xpw  = (const float*)d_in[4];
    const float* dtw  = (const float*)d_in[5];
    const float* dtb  = (const float*)d_in[6];
    const float* Alog = (const float*)d_in[7];
    const float* Ds   = (const float*)d_in[8];
    const float* lng  = (const float*)d_in[9];
    const float* lnb  = (const float*)d_in[10];
    const float* Wout = (const float*)d_in[11];
    float* out = (float*)d_out;

    float* ws = (float*)d_ws;
    size_t off = 0;
    unsigned short* Wi_hi = (unsigned short*)(ws + off); off += 384 * 96 / 2;
    unsigned short* Wi_lo = (unsigned short*)(ws + off); off += 384 * 96 / 2;
    unsigned short* Xp_hi = (unsigned short*)(ws + off); off += 4 * 48 * 192 / 2;
    unsigned short* Xp_lo = (unsigned short*)(ws + off); off += 4 * 48 * 192 / 2;
    unsigned short* Wo_bf = (unsigned short*)(ws + off); off += 96 * DINNER / 2;
    float* xin   = ws + off; off += (size_t)NPIX * 192;
    unsigned short* zb = (unsigned short*)(ws + off); off += (size_t)NPIX * 192 / 2;
    float* xg    = ws + off; off += (size_t)NPIX * 192;
    float* dtrb  = ws + off; off += (size_t)NBK * LP * 6;
    float* Bm    = ws + off; off += (size_t)NBK * LP * 16;
    float* Cm    = ws + off; off += (size_t)NBK * LP * 16;
    float* Sbuf  = ws + off; off += (size_t)NCH * SSTRIDE;
    unsigned short* Qb  = (unsigned short*)(ws + off); off += (size_t)NCH * NSTATES / 2;
    unsigned short* Hst = (unsigned short*)(ws + off); off += (size_t)NCH * NSTATES / 2;
    unsigned short* yout = (unsigned short*)(ws + off); off += (size_t)NBK * LP * 192 / 2;

    hipLaunchKernelGGL(k_castW, dim3(144), dim3(256), 0, stream,
                       W_in, xpw, Wout, Wi_hi, Wi_lo, Xp_hi, Xp_lo, Wo_bf);
    hipLaunchKernelGGL(k_inproj3, dim3(NPIX / 16), dim3(256), 0, stream,
                       x, Wi_hi, Wi_lo, xin, zb);
    hipLaunchKernelGGL(k_conv8, dim3(NPIX / 8), dim3(192), 0, stream,
                       xin, cw, cb, xg);
    hipLaunchKernelGGL(k_xdbl, dim3(NBK * 64), dim3(192), 0, stream,
                       xg, Xp_hi, Xp_lo, dtrb, Bm, Cm);
    hipLaunchKernelGGL(k_scan1y, dim3(NBK * NCH), dim3(192), 0, stream,
                       xg, dtrb, Bm, Cm, Alog, dtw, dtb, Ds, Sbuf, Qb, yout);
    hipLaunchKernelGGL(k_scan2, dim3(NSTATES / 256), dim3(256), 0, stream,
                       Sbuf, Alog, Qb, Hst);
    hipLaunchKernelGGL(k_scan3c, dim3(NBK * NCH), dim3(192), 0, stream,
                       dtrb, Cm, Alog, dtw, dtb, Hst, yout);
    hipLaunchKernelGGL(k_lnout, dim3(NPIX / 32), dim3(256), 0, stream,
                       yout, zb, lng, lnb, Wo_bf, out);
}